// Round 13
// baseline (244.578 us; speedup 1.0000x reference)
//
#include <hip/hip_runtime.h>
#include <math.h>

#define BB 2
#define TT 1024
#define CC 1024
#define HH 16
#define HD 64
#define MM (BB*TT)   // 2048 rows

typedef unsigned short u16;
typedef unsigned int u32;
typedef short s16x8 __attribute__((ext_vector_type(8)));
typedef float f32x4 __attribute__((ext_vector_type(4)));

__device__ __forceinline__ u16 f2bf(float f) {
    u32 u = __builtin_bit_cast(u32, f);
    u += 0x7fffu + ((u >> 16) & 1u);
    return (u16)(u >> 16);
}
__device__ __forceinline__ float bf2f(u16 h) {
    return __builtin_bit_cast(float, ((u32)h) << 16);
}
__device__ __forceinline__ void gload16(const void* g, void* l) {
    __builtin_amdgcn_global_load_lds((const __attribute__((address_space(1))) u32*)g,
                                     (__attribute__((address_space(3))) u32*)l, 16, 0, 0);
}
__device__ __forceinline__ float gelu_tanh(float x) {
    float x3 = x * x * x;
    return 0.5f * x * (1.0f + tanhf(0.7978845608028654f * (x + 0.044715f * x3)));
}
__device__ __forceinline__ float elu1(float v) {
    return (v > 0.0f) ? v + 1.0f : expf(v);
}

// ------------------------------------------------- fused prep:
// [0,4096): weight transpose fp32[K][N]->bf16[N][K]; [4096,6144): memory f2b;
// [6144,6272): RoPE tables; [6272,8320): LN1 (x -> hB bf16)
__device__ __forceinline__ void wtile(const float* __restrict__ in, u16* __restrict__ out,
                                      int K, int N, int local, float (*tl)[65]) {
    int tilesX = N >> 6;
    int n0 = (local % tilesX) * 64, k0 = (local / tilesX) * 64;
    int c = threadIdx.x & 63, r4 = threadIdx.x >> 6;
    #pragma unroll
    for (int i = 0; i < 16; ++i) {
        int r = r4 * 16 + i;
        tl[r][c] = in[(size_t)(k0 + r) * N + n0 + c];
    }
    __syncthreads();
    #pragma unroll
    for (int i = 0; i < 16; ++i) {
        int r = r4 * 16 + i;
        out[(size_t)(n0 + r) * K + k0 + c] = f2bf(tl[c][r]);
    }
}

__global__ __launch_bounds__(256) void prep_kernel(
        const float* __restrict__ w_qkv, u16* __restrict__ t_qkv,
        const float* __restrict__ w_pr,  u16* __restrict__ t_pr,
        const float* __restrict__ w_caq, u16* __restrict__ t_caq,
        const float* __restrict__ w_cakv,u16* __restrict__ t_cakv,
        const float* __restrict__ w_capr,u16* __restrict__ t_capr,
        const float* __restrict__ w_fc,  u16* __restrict__ t_fc,
        const float* __restrict__ w_fcp, u16* __restrict__ t_fcp,
        const float* __restrict__ memF,  u16* __restrict__ memB,
        float* __restrict__ cosT, float* __restrict__ sinT,
        const float* __restrict__ x, const float* __restrict__ ln1_g,
        const float* __restrict__ ln1_b, u16* __restrict__ hB) {
    __shared__ float tl[64][65];
    int bid = blockIdx.x;
    if (bid < 768)        wtile(w_qkv,  t_qkv,  1024, 3072, bid, tl);
    else if (bid < 1024)  wtile(w_pr,   t_pr,   1024, 1024, bid - 768, tl);
    else if (bid < 1280)  wtile(w_caq,  t_caq,  1024, 1024, bid - 1024, tl);
    else if (bid < 1792)  wtile(w_cakv, t_cakv, 1024, 2048, bid - 1280, tl);
    else if (bid < 2048)  wtile(w_capr, t_capr, 1024, 1024, bid - 1792, tl);
    else if (bid < 3072)  wtile(w_fc,   t_fc,   1024, 4096, bid - 2048, tl);
    else if (bid < 4096)  wtile(w_fcp,  t_fcp,  4096, 1024, bid - 3072, tl);
    else if (bid < 6144) {
        int i = (bid - 4096) * 256 + threadIdx.x;
        float4 v = reinterpret_cast<const float4*>(memF)[i];
        uint2 p;
        p.x = (u32)f2bf(v.x) | ((u32)f2bf(v.y) << 16);
        p.y = (u32)f2bf(v.z) | ((u32)f2bf(v.w) << 16);
        reinterpret_cast<uint2*>(memB)[i] = p;
    } else if (bid < 6272) {
        int idx = (bid - 6144) * 256 + threadIdx.x;   // 0..32767
        int t = idx >> 5, d = idx & 31;
        double inv = pow(10000.0, -((double)d) / 32.0);
        double ang = (double)t * inv;
        cosT[t * 32 + d] = (float)cos(ang);
        sinT[t * 32 + d] = (float)sin(ang);
    } else {
        // LayerNorm 1: row = bid - 6272
        int row = bid - 6272;
        float4 v = reinterpret_cast<const float4*>(x + (size_t)row * CC)[threadIdx.x];
        float s  = v.x + v.y + v.z + v.w;
        float sq = v.x*v.x + v.y*v.y + v.z*v.z + v.w*v.w;
        #pragma unroll
        for (int off = 32; off >= 1; off >>= 1) {
            s  += __shfl_down(s, off);
            sq += __shfl_down(sq, off);
        }
        __shared__ float ls[4], lsq[4];
        int wave = threadIdx.x >> 6, lane = threadIdx.x & 63;
        if (lane == 0) { ls[wave] = s; lsq[wave] = sq; }
        __syncthreads();
        s  = ls[0] + ls[1] + ls[2] + ls[3];
        sq = lsq[0] + lsq[1] + lsq[2] + lsq[3];
        float mean = s * (1.0f / CC);
        float var  = sq * (1.0f / CC) - mean * mean;
        float rstd = rsqrtf(var + 1e-5f);
        float4 gv = reinterpret_cast<const float4*>(ln1_g)[threadIdx.x];
        float4 bv = reinterpret_cast<const float4*>(ln1_b)[threadIdx.x];
        float o0 = (v.x - mean) * rstd * gv.x + bv.x;
        float o1 = (v.y - mean) * rstd * gv.y + bv.y;
        float o2 = (v.z - mean) * rstd * gv.z + bv.z;
        float o3 = (v.w - mean) * rstd * gv.w + bv.w;
        uint2 p;
        p.x = (u32)f2bf(o0) | ((u32)f2bf(o1) << 16);
        p.y = (u32)f2bf(o2) | ((u32)f2bf(o3) << 16);
        reinterpret_cast<uint2*>(hB + (size_t)row * CC)[threadIdx.x] = p;
    }
}

// ---------------------------------------------------------------- bf16 MFMA GEMM
#define M_F32RES 0
#define M_GELU   1
#define M_QKV    2
#define M_PART   5
#define M_CAQKV  6

template <int MODE>
__device__ __forceinline__ void emit(int row, int col, float v,
                                     const float* __restrict__ res,
                                     float* __restrict__ oF, u16* __restrict__ o1,
                                     u16* __restrict__ o2, u16* __restrict__ o3, int N) {
    if constexpr (MODE == M_F32RES) {
        size_t o = (size_t)row * N + col;
        oF[o] = v + res[o];
    } else if constexpr (MODE == M_GELU) {
        o1[(size_t)row * N + col] = f2bf(gelu_tanh(v));
    } else {  // M_QKV mapping; all packs row-major [bh][t][d] (coalesced)
        int b = row >> 10, t = row & 1023;
        if (col < 1024) {
            int h = col >> 6, d = col & 63;
            o1[(((size_t)(b * HH + h)) * TT + t) * HD + d] = f2bf(elu1(v));
        } else if (col < 2048) {
            int c = col - 1024, h = c >> 6, d = c & 63;
            o2[(((size_t)(b * HH + h)) * TT + t) * HD + d] = f2bf(elu1(v));
        } else {
            int c = col - 2048, h = c >> 6, d = c & 63;
            o3[(((size_t)(b * HH + h)) * TT + t) * HD + d] = f2bf(v);   // V row-major
        }
    }
}

// out = A[M,K] @ BT[N,K]^T (+bias). 512 threads / 8 waves (4x2), BK=64.
// Single-buffer LDS 2-phase (verified structure; dbuf/counted-vmcnt regressed).
// XCD-aware tile swizzle; XOR-swizzled LDS via pre-swizzled global source.
template <int BM, int BN, int MODE, int SPLITK>
__global__ __launch_bounds__(512, 8) void gemm_bf16(const u16* __restrict__ A,
                                                    const u16* __restrict__ A2,
                                                    const u16* __restrict__ BT,
                                                    const u16* __restrict__ BT2,
                                                    const float* __restrict__ bias,
                                                    const float* __restrict__ bias2,
                                                    const float* __restrict__ res,
                                                    float* __restrict__ oF,
                                                    u16* __restrict__ o1,
                                                    u16* __restrict__ o2,
                                                    u16* __restrict__ o3,
                                                    float* __restrict__ ksumP,
                                                    int N, int K) {
    constexpr int WM = BM / 4, WN = BN / 2;
    constexpr int FI = WM / 16, FJ = WN / 16;
    constexpr int IA = BM * 8 / 512;
    constexpr int IB = BN * 8 / 512;
    __shared__ u16 As[BM * 64];
    __shared__ u16 Bs[BN * 64];
    int tid = threadIdx.x;
    int wave = tid >> 6, lane = tid & 63;
    int wr = wave >> 1, wc = wave & 1;
    int gx = gridDim.x, gy = gridDim.y;
    int lid = blockIdx.x + gx * blockIdx.y;
    int chunk = (gx * gy) >> 3;
    int swz = (lid & 7) * chunk + (lid >> 3);
    int bx = swz % gx, by = swz / gx;
    int row0 = by * BM, col0 = bx * BN;
    const u16* Ause = A;
    const u16* Buse = BT;
    const float* buse = bias;
    if constexpr (MODE == M_CAQKV) {
        if (col0 >= 1024) {
            Ause = A2;
            Buse = BT2 - (size_t)1024 * K;
            buse = bias2 - 1024;
        }
    }
    int kbeg = 0, kcnt = K;
    if constexpr (SPLITK > 1) { kcnt = K / SPLITK; kbeg = blockIdx.z * kcnt; }
    int kend = kbeg + kcnt;

    f32x4 acc[FI][FJ] = {};
    int lr = lane & 15;
    for (int kt = kbeg; kt < kend; kt += 64) {
        __syncthreads();
        #pragma unroll
        for (int i = 0; i < IA; ++i) {
            int s = tid + i * 512;
            int r = s >> 3, kb = s & 7;
            int kbs = kb ^ (r & 7);
            gload16(Ause + (size_t)(row0 + r) * K + kt + kbs * 8, &As[s * 8]);
        }
        #pragma unroll
        for (int i = 0; i < IB; ++i) {
            int s = tid + i * 512;
            int r = s >> 3, kb = s & 7;
            int kbs = kb ^ (r & 7);
            gload16(Buse + (size_t)(col0 + r) * K + kt + kbs * 8, &Bs[s * 8]);
        }
        __syncthreads();
        #pragma unroll
        for (int ks = 0; ks < 2; ++ks) {
            s16x8 a[FI], b[FJ];
            int kc = ks * 4 + (lane >> 4);
            int sw = (kc ^ (lr & 7)) * 8;
            #pragma unroll
            for (int i = 0; i < FI; ++i)
                a[i] = *reinterpret_cast<const s16x8*>(&As[(wr * WM + i * 16 + lr) * 64 + sw]);
            #pragma unroll
            for (int j = 0; j < FJ; ++j)
                b[j] = *reinterpret_cast<const s16x8*>(&Bs[(wc * WN + j * 16 + lr) * 64 + sw]);
            __builtin_amdgcn_s_setprio(1);
            #pragma unroll
            for (int i = 0; i < FI; ++i)
                #pragma unroll
                for (int j = 0; j < FJ; ++j)
                    acc[i][j] = __builtin_amdgcn_mfma_f32_16x16x32_bf16(a[i], b[j], acc[i][j], 0, 0, 0);
            __builtin_amdgcn_s_setprio(0);
        }
    }
    int lr4 = (lane >> 4) * 4;
    if constexpr (MODE == M_PART) {
        size_t zoff = (size_t)blockIdx.z * (size_t)(gridDim.y * BM) * N;
        #pragma unroll
        for (int j = 0; j < FJ; ++j) {
            int col = col0 + wc * WN + j * 16 + lr;
            #pragma unroll
            for (int i = 0; i < FI; ++i)
                #pragma unroll
                for (int r = 0; r < 4; ++r) {
                    int row = row0 + wr * WM + i * 16 + lr4 + r;
                    oF[zoff + (size_t)row * N + col] = acc[i][j][r];
                }
        }
    } else {
        constexpr int EM = (MODE == M_CAQKV) ? M_QKV : MODE;
        #pragma unroll
        for (int j = 0; j < FJ; ++j) {
            int col = col0 + wc * WN + j * 16 + lr;
            float bi = buse[col];
            #pragma unroll
            for (int i = 0; i < FI; ++i)
                #pragma unroll
                for (int r = 0; r < 4; ++r) {
                    int row = row0 + wr * WM + i * 16 + lr4 + r;
                    emit<EM>(row, col, acc[i][j][r] + bi, res, oF, o1, o2, o3, N);
                }
        }
        if constexpr (MODE == M_QKV || MODE == M_CAQKV) {
            if (col0 >= 1024 && col0 < 2048) {
                float* scratch = (float*)As;
                float part[FJ];
                #pragma unroll
                for (int j = 0; j < FJ; ++j) {
                    int col = col0 + wc * WN + j * 16 + lr;
                    float bi = buse[col];
                    float p = 0.f;
                    #pragma unroll
                    for (int i = 0; i < FI; ++i)
                        #pragma unroll
                        for (int r = 0; r < 4; ++r)
                            p += elu1(acc[i][j][r] + bi);
                    part[j] = p;
                }
                __syncthreads();
                int contrib = wr * 4 + (lane >> 4);
                #pragma unroll
                for (int j = 0; j < FJ; ++j) {
                    int colLocal = wc * WN + j * 16 + lr;
                    scratch[colLocal * 16 + contrib] = part[j];
                }
                __syncthreads();
                if (tid < BN) {
                    float s = 0.f;
                    #pragma unroll
                    for (int c = 0; c < 16; ++c) s += scratch[tid * 16 + c];
                    ksumP[(size_t)by * 1024 + (col0 - 1024) + tid] = s;
                }
            }
        }
    }
}

// split-K reduce: out = sum_s P[s] + bias + res
template <int S>
__global__ __launch_bounds__(256) void reduce_res_kernel(const float* __restrict__ P,
                                                         const float* __restrict__ bias,
                                                         const float* __restrict__ res,
                                                         float* __restrict__ out,
                                                         int N, int total4) {
    int idx = blockIdx.x * 256 + threadIdx.x;
    if (idx >= total4) return;
    float4 b = reinterpret_cast<const float4*>(bias)[idx & (N / 4 - 1)];
    float4 r = reinterpret_cast<const float4*>(res)[idx];
    float4 a = {b.x + r.x, b.y + r.y, b.z + r.z, b.w + r.w};
    #pragma unroll
    for (int s = 0; s < S; ++s) {
        float4 p = reinterpret_cast<const float4*>(P)[(size_t)s * total4 + idx];
        a.x += p.x; a.y += p.y; a.z += p.z; a.w += p.w;
    }
    reinterpret_cast<float4*>(out)[idx] = a;
}

// fused: out = sum_s P[s] + bias + res ; hout = LN(out)*g + b (bf16)
template <int S>
__global__ __launch_bounds__(256) void reduce_ln_kernel(const float* __restrict__ P,
                                                        const float* __restrict__ bias,
                                                        const float* __restrict__ res,
                                                        const float* __restrict__ g,
                                                        const float* __restrict__ bta,
                                                        float* __restrict__ out,
                                                        u16* __restrict__ hout) {
    int row = blockIdx.x;
    int t = threadIdx.x;
    const int total4 = MM * CC / 4;
    size_t ro4 = (size_t)row * 256 + t;
    float4 b = reinterpret_cast<const float4*>(bias)[t];
    float4 r = reinterpret_cast<const float4*>(res)[ro4];
    float4 a = {b.x + r.x, b.y + r.y, b.z + r.z, b.w + r.w};
    #pragma unroll
    for (int s = 0; s < S; ++s) {
        float4 p = reinterpret_cast<const float4*>(P)[(size_t)s * total4 + ro4];
        a.x += p.x; a.y += p.y; a.z += p.z; a.w += p.w;
    }
    reinterpret_cast<float4*>(out)[ro4] = a;
    float s1 = a.x + a.y + a.z + a.w;
    float sq = a.x*a.x + a.y*a.y + a.z*a.z + a.w*a.w;
    #pragma unroll
    for (int off = 32; off >= 1; off >>= 1) {
        s1 += __shfl_down(s1, off);
        sq += __shfl_down(sq, off);
    }
    __shared__ float ls[4], lsq[4];
    int wave = t >> 6, lane = t & 63;
    if (lane == 0) { ls[wave] = s1; lsq[wave] = sq; }
    __syncthreads();
    s1 = ls[0] + ls[1] + ls[2] + ls[3];
    sq = lsq[0] + lsq[1] + lsq[2] + lsq[3];
    float mean = s1 * (1.0f / CC);
    float var  = sq * (1.0f / CC) - mean * mean;
    float rstd = rsqrtf(var + 1e-5f);
    float4 gv = reinterpret_cast<const float4*>(g)[t];
    float4 bv = reinterpret_cast<const float4*>(bta)[t];
    float o0 = (a.x - mean) * rstd * gv.x + bv.x;
    float o1 = (a.y - mean) * rstd * gv.y + bv.y;
    float o2 = (a.z - mean) * rstd * gv.z + bv.z;
    float o3 = (a.w - mean) * rstd * gv.w + bv.w;
    uint2 pk;
    pk.x = (u32)f2bf(o0) | ((u32)f2bf(o1) << 16);
    pk.y = (u32)f2bf(o2) | ((u32)f2bf(o3) << 16);
    reinterpret_cast<uint2*>(hout + (size_t)row * CC)[t] = pk;
}

// In-place RoPE of one (row, quarter) of a [bh][T][64] bf16 buffer
__device__ __forceinline__ void rope_row(u16* __restrict__ buf, int bh, int t, int q,
                                         const float* __restrict__ cosT,
                                         const float* __restrict__ sinT) {
    int d0 = q * 8;
    size_t base = ((size_t)bh * TT + t) * HD;
    s16x8 lo = *reinterpret_cast<const s16x8*>(&buf[base + d0]);
    s16x8 hi = *reinterpret_cast<const s16x8*>(&buf[base + 32 + d0]);
    const float4* cp = reinterpret_cast<const float4*>(&cosT[t * 32 + d0]);
    const float4* sp = reinterpret_cast<const float4*>(&sinT[t * 32 + d0]);
    float4 c0 = cp[0], c1 = cp[1], s0 = sp[0], s1 = sp[1];
    float cc[8] = {c0.x, c0.y, c0.z, c0.w, c1.x, c1.y, c1.z, c1.w};
    float ss[8] = {s0.x, s0.y, s0.z, s0.w, s1.x, s1.y, s1.z, s1.w};
    s16x8 nlo, nhi;
    #pragma unroll
    for (int e = 0; e < 8; ++e) {
        float l = bf2f((u16)lo[e]), h = bf2f((u16)hi[e]);
        nlo[e] = (short)f2bf(l * cc[e] - h * ss[e]);
        nhi[e] = (short)f2bf(h * cc[e] + l * ss[e]);
    }
    *reinterpret_cast<s16x8*>(&buf[base + d0]) = nlo;
    *reinterpret_cast<s16x8*>(&buf[base + 32 + d0]) = nhi;
}

// fused: blocks [0,1024): den[bh][t] = Q.Ksum (pre-rope), then rope Q rows;
//        blocks [1024,1536): rope K
__global__ __launch_bounds__(256) void denom_rope_kernel(u16* __restrict__ Qb,
                                                         u16* __restrict__ Kb,
                                                         const float* __restrict__ KsumP,
                                                         const float* __restrict__ cosT,
                                                         const float* __restrict__ sinT,
                                                         float* __restrict__ den) {
    int bid = blockIdx.x;
    if (bid < 1024) {
        int bh = bid >> 5;
        int b = bh >> 4, h = bh & 15;
        int t0 = (bid & 31) * 32;
        __shared__ float ks[64];
        if (threadIdx.x < 64) {
            float s = 0.f;
            #pragma unroll
            for (int rb = 0; rb < 8; ++rb)
                s += KsumP[(size_t)(b * 8 + rb) * 1024 + h * 64 + threadIdx.x];
            ks[threadIdx.x] = s;
        }
        __syncthreads();
        int wave = threadIdx.x >> 6, lane = threadIdx.x & 63;
        int rw = lane >> 3, lsub = lane & 7;
        int t = t0 + wave * 8 + rw;
        s16x8 q = *reinterpret_cast<const s16x8*>(&Qb[((size_t)bh * TT + t) * HD + lsub * 8]);
        float p = 0.f;
        #pragma unroll
        for (int e = 0; e < 8; ++e) p += bf2f((u16)q[e]) * ks[lsub * 8 + e];
        p += __shfl_xor(p, 1);
        p += __shfl_xor(p, 2);
        p += __shfl_xor(p, 4);
        if (lsub == 0) den[bh * TT + t] = p;
        __syncthreads();   // all denom reads of this block's Q rows complete
        if (threadIdx.x < 128) {
            int row = threadIdx.x >> 2, qq = threadIdx.x & 3;
            rope_row(Qb, bh, t0 + row, qq, cosT, sinT);
        }
    } else {
        int g = (bid - 1024) * 256 + threadIdx.x;   // 0..131071
        int qq = g & 3;
        int t = (g >> 2) & 1023;
        int bh = g >> 12;
        rope_row(Kb, bh, t, qq, cosT, sinT);
    }
}

// ------------------------------------------------------- MFMA linear attention
// V input is row-major [bh][T][64]; transpose into Vs[d][s] during LDS staging.
#define APAD 72
__global__ __launch_bounds__(256) void attn_mfma(const u16* __restrict__ Qr,
                                                 const u16* __restrict__ Kr,
                                                 const u16* __restrict__ Vr,
                                                 const float* __restrict__ den,
                                                 u16* __restrict__ out, int causal) {
    __shared__ u16 Qs[64 * APAD];
    __shared__ u16 Ks[64 * APAD];
    __shared__ u16 Vs[64 * APAD];   // [d][s]
    __shared__ u16 Ps[64 * APAD];
    int lid = blockIdx.x + gridDim.x * blockIdx.y;
    int chunk = (gridDim.x * gridDim.y) >> 3;
    int swz = (lid & 7) * chunk + (lid >> 3);
    int tile = swz % gridDim.x;
    int bh = swz / gridDim.x;
    int b = bh >> 4, h = bh & 15;
    int t0 = tile * 64;
    int tid = threadIdx.x, wave = tid >> 6, lane = tid & 63;
    #pragma unroll
    for (int i = 0; i < 2; ++i) {
        int s = tid + i * 256;
        int r = s >> 3, kb = s & 7;
        *reinterpret_cast<s16x8*>(&Qs[r * APAD + kb * 8]) =
            *reinterpret_cast<const s16x8*>(&Qr[((size_t)bh * TT + t0 + r) * HD + kb * 8]);
    }
    __syncthreads();
    int lr = lane & 15, lk = (lane >> 4) * 8;
    s16x8 qf0 = *reinterpret_cast<const s16x8*>(&Qs[(wave * 16 + lr) * APAD + lk]);
    s16x8 qf1 = *reinterpret_cast<const s16x8*>(&Qs[(wave * 16 + lr) * APAD + 32 + lk]);
    f32x4 accO[4] = {};
    int ntiles = causal ? (tile + 1) : (TT / 64);
    for (int st = 0; st < ntiles; ++st) {
        int s0 = st * 64;
        __syncthreads();
        #pragma unroll
        for (int i = 0; i < 2; ++i) {
            int s = tid + i * 256;
            int r = s >> 3, kb = s & 7;
            *reinterpret_cast<s16x8*>(&Ks[r * APAD + kb * 8]) =
                *reinterpret_cast<const s16x8*>(&Kr[((size_t)bh * TT + s0 + r) * HD + kb * 8]);
            s16x8 vv = *reinterpret_cast<const s16x8*>(&Vr[((size_t)bh * TT + s0 + r) * HD + kb * 8]);
            #pragma unroll
            for (int e = 0; e < 8; ++e)
                Vs[(kb * 8 + e) * APAD + r] = (u16)vv[e];   // transpose to [d][s]
        }
        __syncthreads();
        f32x4 accS[4] = {};
        __builtin_amdgcn_s_setprio(1);
        #pragma unroll
        for (int j = 0; j < 4; ++j) {
            s16x8 kb0 = *reinterpret_cast<const s16x8*>(&Ks[(j * 16 + lr) * APAD + lk]);
            s16x8 kb1 = *reinterpret_cast<const s16x8*>(&Ks[(j * 16 + lr) * APAD + 32 + lk]);
            accS[j] = __builtin_amdgcn_mfma_f32_16x16x32_bf16(qf0, kb0, accS[j], 0, 0, 0);
            accS[j] = __builtin_amdgcn_mfma_f32_16x16x32_bf16(qf1, kb1, accS[j], 0, 0, 0);
        }
        __builtin_amdgcn_s_setprio(0);
        int tl = wave * 16 + (lane >> 4) * 4;
        #pragma unroll
        for (int j = 0; j < 4; ++j) {
            #pragma unroll
            for (int r = 0; r < 4; ++r) {
                float v = accS[j][r];
                if (causal && (s0 + j * 16 + lr > t0 + tl + r)) v = 0.f;
                Ps[(tl + r) * APAD + j * 16 + lr] = f2bf(v);
            }
        }
        __syncthreads();
        __builtin_amdgcn_s_setprio(1);
        #pragma unroll
        for (int ks = 0; ks < 2; ++ks) {
            s16x8 pa = *reinterpret_cast<const s16x8*>(&Ps[(wave * 16 + lr) * APAD + ks * 32 + lk]);
            #pragma unroll
            for (int j = 0; j < 4; ++j) {
                s16x8 vb = *reinterpret_cast<const s16x8*>(&Vs[(j * 16 + lr) * APAD + ks * 32 + lk]);
                accO[j] = __builtin_amdgcn_mfma_f32_16x16x32_bf16(pa, vb, accO[j], 0, 0, 0);
            }
        }
        __builtin_amdgcn_s_setprio(0);
    }
    int tl = wave * 16 + (lane >> 4) * 4;
    float invd[4];
    #pragma unroll
    for (int r = 0; r < 4; ++r) invd[r] = 1.0f / den[bh * TT + t0 + tl + r];
    #pragma unroll
    for (int j = 0; j < 4; ++j)
        #pragma unroll
        for (int r = 0; r < 4; ++r)
            out[(size_t)(b * TT + t0 + tl + r) * CC + h * HD + j * 16 + lr] = f2bf(accO[j][r] * invd[r]);
}

// ---------------------------------------------------------------- launch
extern "C" void kernel_launch(void* const* d_in, const int* in_sizes, int n_in,
                              void* d_out, int out_size, void* d_ws, size_t ws_size,
                              hipStream_t stream) {
    const float* x        = (const float*)d_in[0];
    const float* memory   = (const float*)d_in[1];
    const float* ln1_g    = (const float*)d_in[2];
    const float* ln1_b    = (const float*)d_in[3];
    const float* sa_qkv_w = (const float*)d_in[4];
    const float* sa_qkv_b = (const float*)d_in[5];
    const float* sa_pr_w  = (const float*)d_in[6];
    const float* sa_pr_b  = (const float*)d_in[7];
    const float* ln2_g    = (const float*)d_in[8];
    const float* ln2_b    = (const float*)d_in[9];
    const float* ca_q_w   = (const float*)d_in[10];
    const float* ca_q_b   = (const float*)d_in[11];
    const float* ca_kv_w  = (const float*)d_in[12];
    const float* ca_kv_b  = (const float*)d_in[13];
    const float* ca_pr_w  = (const float*)d_in[14];
    const float* ca_pr_b  = (const float*)d_in[15];
    const float* ln3_g    = (const float*)d_in[16];
    const float* ln3_b    = (const float*)d_in[17];
    const float* fc_w     = (const float*)d_in[18];
    const float* fc_b     = (const float*)d_in[19];
    const float* fcp_w    = (const float*)d_in[20];
    const float* fcp_b    = (const float*)d_in[21];
    float* out = (float*)d_out;
    char* wsb  = (char*)d_ws;

    const size_t MB = 1024 * 1024;
    u16* qkvT  = (u16*)wsb;                  // 6 MB
    u16* prT   = (u16*)(wsb + 6 * MB);       // 2 MB
    u16* caqT  = (u16*)(wsb + 8 * MB);       // 2 MB
    u16* cakvT = (u16*)(wsb + 10 * MB);      // 4 MB
    u16* caprT = (u16*)(wsb + 14 * MB);      // 2 MB
    u16* fcT   = (u16*)(wsb + 16 * MB);      // 8 MB
    u16* fcpT  = (u16*)(wsb + 24 * MB);      // 8 MB
    u16* memB  = (u16*)(wsb + 32 * MB);      // 4 MB
    u16* hB    = (u16*)(wsb + 36 * MB);      // 4 MB
    u16* h2B   = (u16*)(wsb + 40 * MB);      // 4 MB
    u16* Qb    = (u16*)(wsb + 44 * MB);      // 4 MB
    u16* Kb    = (u16*)(wsb + 48 * MB);      // 4 MB
    u16* Vb    = (u16*)(wsb + 52 * MB);      // 4 MB (row-major V)
    float* Pbuf = (float*)(wsb + 44 * MB);   // 16 MB (SPLITK=2 projections), aliases Q/K/V after attn
    u16*   fcB   = (u16*)wsb;                // 16 MB at [0,16) (qkvT..caprT dead by MLP)
    float* Pbuf4 = (float*)(wsb + 40 * MB);  // 32 MB at [40,72) (MLP only)
    float* KsumP = (float*)(wsb + 76 * MB + 65536);    // 64 KB
    float* den   = (float*)(wsb + 76 * MB + 131072);   // 128 KB
    float* cosT  = (float*)(wsb + 76 * MB + 262144);   // 128 KB
    float* sinT  = (float*)(wsb + 76 * MB + 393216);   // 128 KB

    dim3 b256(256), b512(512);
    const int TOT4 = MM * CC / 4;  // 524288

    // fused prep: weight transposes + memory f2b + RoPE tables + LN1
    prep_kernel<<<dim3(8320), b256, 0, stream>>>(
        sa_qkv_w, qkvT, sa_pr_w, prT, ca_q_w, caqT, ca_kv_w, cakvT,
        ca_pr_w, caprT, fc_w, fcT, fcp_w, fcpT, memory, memB, cosT, sinT,
        x, ln1_g, ln1_b, hB);

    // ---- causal self-attention ----
    gemm_bf16<128, 64, M_QKV, 1><<<dim3(48, 16), b512, 0, stream>>>(
        hB, nullptr, qkvT, nullptr, sa_qkv_b, nullptr, nullptr,
        nullptr, Qb, Kb, Vb, KsumP, 3072, 1024);
    denom_rope_kernel<<<dim3(1536), b256, 0, stream>>>(Qb, Kb, KsumP, cosT, sinT, den);
    attn_mfma<<<dim3(16, 32), b256, 0, stream>>>(Qb, Kb, Vb, den, h2B, 1);
    gemm_bf16<64, 64, M_PART, 2><<<dim3(16, 32, 2), b512, 0, stream>>>(
        h2B, nullptr, prT, nullptr, nullptr, nullptr, nullptr,
        Pbuf, nullptr, nullptr, nullptr, nullptr, 1024, 1024);
    reduce_ln_kernel<2><<<dim3(MM), b256, 0, stream>>>(Pbuf, sa_pr_b, x, ln2_g, ln2_b, out, hB);

    // ---- cross-attention ----
    gemm_bf16<128, 64, M_CAQKV, 1><<<dim3(48, 16), b512, 0, stream>>>(
        hB, memB, caqT, cakvT, ca_q_b, ca_kv_b, nullptr,
        nullptr, Qb, Kb, Vb, KsumP, 3072, 1024);
    denom_rope_kernel<<<dim3(1536), b256, 0, stream>>>(Qb, Kb, KsumP, cosT, sinT, den);
    attn_mfma<<<dim3(16, 32), b256, 0, stream>>>(Qb, Kb, Vb, den, h2B, 0);
    gemm_bf16<64, 64, M_PART, 2><<<dim3(16, 32, 2), b512, 0, stream>>>(
        h2B, nullptr, caprT, nullptr, nullptr, nullptr, nullptr,
        Pbuf, nullptr, nullptr, nullptr, nullptr, 1024, 1024);
    reduce_ln_kernel<2><<<dim3(MM), b256, 0, stream>>>(Pbuf, ca_pr_b, out, ln3_g, ln3_b, out, hB);

    // ---- MLP ----
    gemm_bf16<128, 64, M_GELU, 1><<<dim3(64, 16), b512, 0, stream>>>(
        hB, nullptr, fcT, nullptr, fc_b, nullptr, nullptr,
        nullptr, fcB, nullptr, nullptr, nullptr, 4096, 1024);
    gemm_bf16<128, 64, M_PART, 4><<<dim3(16, 16, 4), b512, 0, stream>>>(
        fcB, nullptr, fcpT, nullptr, nullptr, nullptr, nullptr,
        Pbuf4, nullptr, nullptr, nullptr, nullptr, 1024, 4096);
    reduce_res_kernel<4><<<dim3(TOT4 / 256), b256, 0, stream>>>(Pbuf4, fcp_b, out, out, 1024, TOT4);
}

// Round 14
// 225.287 us; speedup vs baseline: 1.0856x; 1.0856x over previous
//
#include <hip/hip_runtime.h>
#include <math.h>

#define BB 2
#define TT 1024
#define CC 1024
#define HH 16
#define HD 64
#define MM (BB*TT)   // 2048 rows

typedef unsigned short u16;
typedef unsigned int u32;
typedef short s16x8 __attribute__((ext_vector_type(8)));
typedef float f32x4 __attribute__((ext_vector_type(4)));

__device__ __forceinline__ u16 f2bf(float f) {
    u32 u = __builtin_bit_cast(u32, f);
    u += 0x7fffu + ((u >> 16) & 1u);
    return (u16)(u >> 16);
}
__device__ __forceinline__ float bf2f(u16 h) {
    return __builtin_bit_cast(float, ((u32)h) << 16);
}
__device__ __forceinline__ void gload16(const void* g, void* l) {
    __builtin_amdgcn_global_load_lds((const __attribute__((address_space(1))) u32*)g,
                                     (__attribute__((address_space(3))) u32*)l, 16, 0, 0);
}
__device__ __forceinline__ float gelu_tanh(float x) {
    float x3 = x * x * x;
    return 0.5f * x * (1.0f + tanhf(0.7978845608028654f * (x + 0.044715f * x3)));
}
__device__ __forceinline__ float elu1(float v) {
    return (v > 0.0f) ? v + 1.0f : expf(v);
}

// ------------------------------------------------- fused prep:
// [0,4096): weight transpose fp32[K][N]->bf16[N][K]; [4096,6144): memory f2b;
// [6144,6272): RoPE tables; [6272,8320): LN1 (x -> hB bf16)
__device__ __forceinline__ void wtile(const float* __restrict__ in, u16* __restrict__ out,
                                      int K, int N, int local, float (*tl)[65]) {
    int tilesX = N >> 6;
    int n0 = (local % tilesX) * 64, k0 = (local / tilesX) * 64;
    int c = threadIdx.x & 63, r4 = threadIdx.x >> 6;
    #pragma unroll
    for (int i = 0; i < 16; ++i) {
        int r = r4 * 16 + i;
        tl[r][c] = in[(size_t)(k0 + r) * N + n0 + c];
    }
    __syncthreads();
    #pragma unroll
    for (int i = 0; i < 16; ++i) {
        int r = r4 * 16 + i;
        out[(size_t)(n0 + r) * K + k0 + c] = f2bf(tl[c][r]);
    }
}

__global__ __launch_bounds__(256) void prep_kernel(
        const float* __restrict__ w_qkv, u16* __restrict__ t_qkv,
        const float* __restrict__ w_pr,  u16* __restrict__ t_pr,
        const float* __restrict__ w_caq, u16* __restrict__ t_caq,
        const float* __restrict__ w_cakv,u16* __restrict__ t_cakv,
        const float* __restrict__ w_capr,u16* __restrict__ t_capr,
        const float* __restrict__ w_fc,  u16* __restrict__ t_fc,
        const float* __restrict__ w_fcp, u16* __restrict__ t_fcp,
        const float* __restrict__ memF,  u16* __restrict__ memB,
        float* __restrict__ cosT, float* __restrict__ sinT,
        const float* __restrict__ x, const float* __restrict__ ln1_g,
        const float* __restrict__ ln1_b, u16* __restrict__ hB) {
    __shared__ float tl[64][65];
    int bid = blockIdx.x;
    if (bid < 768)        wtile(w_qkv,  t_qkv,  1024, 3072, bid, tl);
    else if (bid < 1024)  wtile(w_pr,   t_pr,   1024, 1024, bid - 768, tl);
    else if (bid < 1280)  wtile(w_caq,  t_caq,  1024, 1024, bid - 1024, tl);
    else if (bid < 1792)  wtile(w_cakv, t_cakv, 1024, 2048, bid - 1280, tl);
    else if (bid < 2048)  wtile(w_capr, t_capr, 1024, 1024, bid - 1792, tl);
    else if (bid < 3072)  wtile(w_fc,   t_fc,   1024, 4096, bid - 2048, tl);
    else if (bid < 4096)  wtile(w_fcp,  t_fcp,  4096, 1024, bid - 3072, tl);
    else if (bid < 6144) {
        int i = (bid - 4096) * 256 + threadIdx.x;
        float4 v = reinterpret_cast<const float4*>(memF)[i];
        uint2 p;
        p.x = (u32)f2bf(v.x) | ((u32)f2bf(v.y) << 16);
        p.y = (u32)f2bf(v.z) | ((u32)f2bf(v.w) << 16);
        reinterpret_cast<uint2*>(memB)[i] = p;
    } else if (bid < 6272) {
        int idx = (bid - 6144) * 256 + threadIdx.x;   // 0..32767
        int t = idx >> 5, d = idx & 31;
        double inv = pow(10000.0, -((double)d) / 32.0);
        double ang = (double)t * inv;
        cosT[t * 32 + d] = (float)cos(ang);
        sinT[t * 32 + d] = (float)sin(ang);
    } else {
        // LayerNorm 1: row = bid - 6272
        int row = bid - 6272;
        float4 v = reinterpret_cast<const float4*>(x + (size_t)row * CC)[threadIdx.x];
        float s  = v.x + v.y + v.z + v.w;
        float sq = v.x*v.x + v.y*v.y + v.z*v.z + v.w*v.w;
        #pragma unroll
        for (int off = 32; off >= 1; off >>= 1) {
            s  += __shfl_down(s, off);
            sq += __shfl_down(sq, off);
        }
        __shared__ float ls[4], lsq[4];
        int wave = threadIdx.x >> 6, lane = threadIdx.x & 63;
        if (lane == 0) { ls[wave] = s; lsq[wave] = sq; }
        __syncthreads();
        s  = ls[0] + ls[1] + ls[2] + ls[3];
        sq = lsq[0] + lsq[1] + lsq[2] + lsq[3];
        float mean = s * (1.0f / CC);
        float var  = sq * (1.0f / CC) - mean * mean;
        float rstd = rsqrtf(var + 1e-5f);
        float4 gv = reinterpret_cast<const float4*>(ln1_g)[threadIdx.x];
        float4 bv = reinterpret_cast<const float4*>(ln1_b)[threadIdx.x];
        float o0 = (v.x - mean) * rstd * gv.x + bv.x;
        float o1 = (v.y - mean) * rstd * gv.y + bv.y;
        float o2 = (v.z - mean) * rstd * gv.z + bv.z;
        float o3 = (v.w - mean) * rstd * gv.w + bv.w;
        uint2 p;
        p.x = (u32)f2bf(o0) | ((u32)f2bf(o1) << 16);
        p.y = (u32)f2bf(o2) | ((u32)f2bf(o3) << 16);
        reinterpret_cast<uint2*>(hB + (size_t)row * CC)[threadIdx.x] = p;
    }
}

// ---------------------------------------------------------------- bf16 MFMA GEMM
#define M_F32RES 0
#define M_GELU   1
#define M_QKV    2
#define M_PART   5
#define M_CAQKV  6

template <int MODE>
__device__ __forceinline__ void emit(int row, int col, float v,
                                     const float* __restrict__ res,
                                     float* __restrict__ oF, u16* __restrict__ o1,
                                     u16* __restrict__ o2, u16* __restrict__ o3, int N) {
    if constexpr (MODE == M_F32RES) {
        size_t o = (size_t)row * N + col;
        oF[o] = v + res[o];
    } else if constexpr (MODE == M_GELU) {
        o1[(size_t)row * N + col] = f2bf(gelu_tanh(v));
    } else {  // M_QKV mapping; all packs row-major [bh][t][d] (coalesced)
        int b = row >> 10, t = row & 1023;
        if (col < 1024) {
            int h = col >> 6, d = col & 63;
            o1[(((size_t)(b * HH + h)) * TT + t) * HD + d] = f2bf(elu1(v));
        } else if (col < 2048) {
            int c = col - 1024, h = c >> 6, d = c & 63;
            o2[(((size_t)(b * HH + h)) * TT + t) * HD + d] = f2bf(elu1(v));
        } else {
            int c = col - 2048, h = c >> 6, d = c & 63;
            o3[(((size_t)(b * HH + h)) * TT + t) * HD + d] = f2bf(v);   // V row-major
        }
    }
}

// out = A[M,K] @ BT[N,K]^T (+bias). 512 threads / 8 waves (4x2), BK=64.
// Single-buffer LDS 2-phase (verified structure; dbuf/counted-vmcnt regressed).
// XCD-aware tile swizzle; XOR-swizzled LDS via pre-swizzled global source.
template <int BM, int BN, int MODE, int SPLITK>
__global__ __launch_bounds__(512, 8) void gemm_bf16(const u16* __restrict__ A,
                                                    const u16* __restrict__ A2,
                                                    const u16* __restrict__ BT,
                                                    const u16* __restrict__ BT2,
                                                    const float* __restrict__ bias,
                                                    const float* __restrict__ bias2,
                                                    const float* __restrict__ res,
                                                    float* __restrict__ oF,
                                                    u16* __restrict__ o1,
                                                    u16* __restrict__ o2,
                                                    u16* __restrict__ o3,
                                                    float* __restrict__ ksumP,
                                                    int N, int K) {
    constexpr int WM = BM / 4, WN = BN / 2;
    constexpr int FI = WM / 16, FJ = WN / 16;
    constexpr int IA = BM * 8 / 512;
    constexpr int IB = BN * 8 / 512;
    __shared__ u16 As[BM * 64];
    __shared__ u16 Bs[BN * 64];
    int tid = threadIdx.x;
    int wave = tid >> 6, lane = tid & 63;
    int wr = wave >> 1, wc = wave & 1;
    int gx = gridDim.x, gy = gridDim.y;
    int lid = blockIdx.x + gx * blockIdx.y;
    int chunk = (gx * gy) >> 3;
    int swz = (lid & 7) * chunk + (lid >> 3);
    int bx = swz % gx, by = swz / gx;
    int row0 = by * BM, col0 = bx * BN;
    const u16* Ause = A;
    const u16* Buse = BT;
    const float* buse = bias;
    if constexpr (MODE == M_CAQKV) {
        if (col0 >= 1024) {
            Ause = A2;
            Buse = BT2 - (size_t)1024 * K;
            buse = bias2 - 1024;
        }
    }
    int kbeg = 0, kcnt = K;
    if constexpr (SPLITK > 1) { kcnt = K / SPLITK; kbeg = blockIdx.z * kcnt; }
    int kend = kbeg + kcnt;

    f32x4 acc[FI][FJ] = {};
    int lr = lane & 15;
    for (int kt = kbeg; kt < kend; kt += 64) {
        __syncthreads();
        #pragma unroll
        for (int i = 0; i < IA; ++i) {
            int s = tid + i * 512;
            int r = s >> 3, kb = s & 7;
            int kbs = kb ^ (r & 7);
            gload16(Ause + (size_t)(row0 + r) * K + kt + kbs * 8, &As[s * 8]);
        }
        #pragma unroll
        for (int i = 0; i < IB; ++i) {
            int s = tid + i * 512;
            int r = s >> 3, kb = s & 7;
            int kbs = kb ^ (r & 7);
            gload16(Buse + (size_t)(col0 + r) * K + kt + kbs * 8, &Bs[s * 8]);
        }
        __syncthreads();
        #pragma unroll
        for (int ks = 0; ks < 2; ++ks) {
            s16x8 a[FI], b[FJ];
            int kc = ks * 4 + (lane >> 4);
            int sw = (kc ^ (lr & 7)) * 8;
            #pragma unroll
            for (int i = 0; i < FI; ++i)
                a[i] = *reinterpret_cast<const s16x8*>(&As[(wr * WM + i * 16 + lr) * 64 + sw]);
            #pragma unroll
            for (int j = 0; j < FJ; ++j)
                b[j] = *reinterpret_cast<const s16x8*>(&Bs[(wc * WN + j * 16 + lr) * 64 + sw]);
            __builtin_amdgcn_s_setprio(1);
            #pragma unroll
            for (int i = 0; i < FI; ++i)
                #pragma unroll
                for (int j = 0; j < FJ; ++j)
                    acc[i][j] = __builtin_amdgcn_mfma_f32_16x16x32_bf16(a[i], b[j], acc[i][j], 0, 0, 0);
            __builtin_amdgcn_s_setprio(0);
        }
    }
    int lr4 = (lane >> 4) * 4;
    if constexpr (MODE == M_PART) {
        size_t zoff = (size_t)blockIdx.z * (size_t)(gridDim.y * BM) * N;
        #pragma unroll
        for (int j = 0; j < FJ; ++j) {
            int col = col0 + wc * WN + j * 16 + lr;
            #pragma unroll
            for (int i = 0; i < FI; ++i)
                #pragma unroll
                for (int r = 0; r < 4; ++r) {
                    int row = row0 + wr * WM + i * 16 + lr4 + r;
                    oF[zoff + (size_t)row * N + col] = acc[i][j][r];
                }
        }
    } else {
        constexpr int EM = (MODE == M_CAQKV) ? M_QKV : MODE;
        #pragma unroll
        for (int j = 0; j < FJ; ++j) {
            int col = col0 + wc * WN + j * 16 + lr;
            float bi = buse[col];
            #pragma unroll
            for (int i = 0; i < FI; ++i)
                #pragma unroll
                for (int r = 0; r < 4; ++r) {
                    int row = row0 + wr * WM + i * 16 + lr4 + r;
                    emit<EM>(row, col, acc[i][j][r] + bi, res, oF, o1, o2, o3, N);
                }
        }
        if constexpr (MODE == M_QKV || MODE == M_CAQKV) {
            if (col0 >= 1024 && col0 < 2048) {
                float* scratch = (float*)As;
                float part[FJ];
                #pragma unroll
                for (int j = 0; j < FJ; ++j) {
                    int col = col0 + wc * WN + j * 16 + lr;
                    float bi = buse[col];
                    float p = 0.f;
                    #pragma unroll
                    for (int i = 0; i < FI; ++i)
                        #pragma unroll
                        for (int r = 0; r < 4; ++r)
                            p += elu1(acc[i][j][r] + bi);
                    part[j] = p;
                }
                __syncthreads();
                int contrib = wr * 4 + (lane >> 4);
                #pragma unroll
                for (int j = 0; j < FJ; ++j) {
                    int colLocal = wc * WN + j * 16 + lr;
                    scratch[colLocal * 16 + contrib] = part[j];
                }
                __syncthreads();
                if (tid < BN) {
                    float s = 0.f;
                    #pragma unroll
                    for (int c = 0; c < 16; ++c) s += scratch[tid * 16 + c];
                    ksumP[(size_t)by * 1024 + (col0 - 1024) + tid] = s;
                }
            }
        }
    }
}

// split-K reduce: out = sum_s P[s] + bias + res
template <int S>
__global__ __launch_bounds__(256) void reduce_res_kernel(const float* __restrict__ P,
                                                         const float* __restrict__ bias,
                                                         const float* __restrict__ res,
                                                         float* __restrict__ out,
                                                         int N, int total4) {
    int idx = blockIdx.x * 256 + threadIdx.x;
    if (idx >= total4) return;
    float4 b = reinterpret_cast<const float4*>(bias)[idx & (N / 4 - 1)];
    float4 r = reinterpret_cast<const float4*>(res)[idx];
    float4 a = {b.x + r.x, b.y + r.y, b.z + r.z, b.w + r.w};
    #pragma unroll
    for (int s = 0; s < S; ++s) {
        float4 p = reinterpret_cast<const float4*>(P)[(size_t)s * total4 + idx];
        a.x += p.x; a.y += p.y; a.z += p.z; a.w += p.w;
    }
    reinterpret_cast<float4*>(out)[idx] = a;
}

// fused: out = sum_s P[s] + bias + res ; hout = LN(out)*g + b (bf16)
template <int S>
__global__ __launch_bounds__(256) void reduce_ln_kernel(const float* __restrict__ P,
                                                        const float* __restrict__ bias,
                                                        const float* __restrict__ res,
                                                        const float* __restrict__ g,
                                                        const float* __restrict__ bta,
                                                        float* __restrict__ out,
                                                        u16* __restrict__ hout) {
    int row = blockIdx.x;
    int t = threadIdx.x;
    const int total4 = MM * CC / 4;
    size_t ro4 = (size_t)row * 256 + t;
    float4 b = reinterpret_cast<const float4*>(bias)[t];
    float4 r = reinterpret_cast<const float4*>(res)[ro4];
    float4 a = {b.x + r.x, b.y + r.y, b.z + r.z, b.w + r.w};
    #pragma unroll
    for (int s = 0; s < S; ++s) {
        float4 p = reinterpret_cast<const float4*>(P)[(size_t)s * total4 + ro4];
        a.x += p.x; a.y += p.y; a.z += p.z; a.w += p.w;
    }
    reinterpret_cast<float4*>(out)[ro4] = a;
    float s1 = a.x + a.y + a.z + a.w;
    float sq = a.x*a.x + a.y*a.y + a.z*a.z + a.w*a.w;
    #pragma unroll
    for (int off = 32; off >= 1; off >>= 1) {
        s1 += __shfl_down(s1, off);
        sq += __shfl_down(sq, off);
    }
    __shared__ float ls[4], lsq[4];
    int wave = t >> 6, lane = t & 63;
    if (lane == 0) { ls[wave] = s1; lsq[wave] = sq; }
    __syncthreads();
    s1 = ls[0] + ls[1] + ls[2] + ls[3];
    sq = lsq[0] + lsq[1] + lsq[2] + lsq[3];
    float mean = s1 * (1.0f / CC);
    float var  = sq * (1.0f / CC) - mean * mean;
    float rstd = rsqrtf(var + 1e-5f);
    float4 gv = reinterpret_cast<const float4*>(g)[t];
    float4 bv = reinterpret_cast<const float4*>(bta)[t];
    float o0 = (a.x - mean) * rstd * gv.x + bv.x;
    float o1 = (a.y - mean) * rstd * gv.y + bv.y;
    float o2 = (a.z - mean) * rstd * gv.z + bv.z;
    float o3 = (a.w - mean) * rstd * gv.w + bv.w;
    uint2 pk;
    pk.x = (u32)f2bf(o0) | ((u32)f2bf(o1) << 16);
    pk.y = (u32)f2bf(o2) | ((u32)f2bf(o3) << 16);
    reinterpret_cast<uint2*>(hout + (size_t)row * CC)[t] = pk;
}

// In-place RoPE of one (row, quarter) of a [bh][T][64] bf16 buffer
__device__ __forceinline__ void rope_row(u16* __restrict__ buf, int bh, int t, int q,
                                         const float* __restrict__ cosT,
                                         const float* __restrict__ sinT) {
    int d0 = q * 8;
    size_t base = ((size_t)bh * TT + t) * HD;
    s16x8 lo = *reinterpret_cast<const s16x8*>(&buf[base + d0]);
    s16x8 hi = *reinterpret_cast<const s16x8*>(&buf[base + 32 + d0]);
    const float4* cp = reinterpret_cast<const float4*>(&cosT[t * 32 + d0]);
    const float4* sp = reinterpret_cast<const float4*>(&sinT[t * 32 + d0]);
    float4 c0 = cp[0], c1 = cp[1], s0 = sp[0], s1 = sp[1];
    float cc[8] = {c0.x, c0.y, c0.z, c0.w, c1.x, c1.y, c1.z, c1.w};
    float ss[8] = {s0.x, s0.y, s0.z, s0.w, s1.x, s1.y, s1.z, s1.w};
    s16x8 nlo, nhi;
    #pragma unroll
    for (int e = 0; e < 8; ++e) {
        float l = bf2f((u16)lo[e]), h = bf2f((u16)hi[e]);
        nlo[e] = (short)f2bf(l * cc[e] - h * ss[e]);
        nhi[e] = (short)f2bf(h * cc[e] + l * ss[e]);
    }
    *reinterpret_cast<s16x8*>(&buf[base + d0]) = nlo;
    *reinterpret_cast<s16x8*>(&buf[base + 32 + d0]) = nhi;
}

// fused: blocks [0,1024): den[bh][t] = Q.Ksum (pre-rope), then rope Q rows;
//        blocks [1024,1536): rope K
__global__ __launch_bounds__(256) void denom_rope_kernel(u16* __restrict__ Qb,
                                                         u16* __restrict__ Kb,
                                                         const float* __restrict__ KsumP,
                                                         const float* __restrict__ cosT,
                                                         const float* __restrict__ sinT,
                                                         float* __restrict__ den) {
    int bid = blockIdx.x;
    if (bid < 1024) {
        int bh = bid >> 5;
        int b = bh >> 4, h = bh & 15;
        int t0 = (bid & 31) * 32;
        __shared__ float ks[64];
        if (threadIdx.x < 64) {
            float s = 0.f;
            #pragma unroll
            for (int rb = 0; rb < 8; ++rb)
                s += KsumP[(size_t)(b * 8 + rb) * 1024 + h * 64 + threadIdx.x];
            ks[threadIdx.x] = s;
        }
        __syncthreads();
        int wave = threadIdx.x >> 6, lane = threadIdx.x & 63;
        int rw = lane >> 3, lsub = lane & 7;
        int t = t0 + wave * 8 + rw;
        s16x8 q = *reinterpret_cast<const s16x8*>(&Qb[((size_t)bh * TT + t) * HD + lsub * 8]);
        float p = 0.f;
        #pragma unroll
        for (int e = 0; e < 8; ++e) p += bf2f((u16)q[e]) * ks[lsub * 8 + e];
        p += __shfl_xor(p, 1);
        p += __shfl_xor(p, 2);
        p += __shfl_xor(p, 4);
        if (lsub == 0) den[bh * TT + t] = p;
        __syncthreads();   // all denom reads of this block's Q rows complete
        if (threadIdx.x < 128) {
            int row = threadIdx.x >> 2, qq = threadIdx.x & 3;
            rope_row(Qb, bh, t0 + row, qq, cosT, sinT);
        }
    } else {
        int g = (bid - 1024) * 256 + threadIdx.x;   // 0..131071
        int qq = g & 3;
        int t = (g >> 2) & 1023;
        int bh = g >> 12;
        rope_row(Kb, bh, t, qq, cosT, sinT);
    }
}

// ------------------------------------------------------- MFMA linear attention
// V input row-major [bh][T][64]; transpose into Vs[d][s'] during staging with a
// kb-XOR chunk swizzle (s' = ((s>>3) ^ (d>>3))*8 + (s&7)) so the 8 kb-lanes of
// each wave spread across banks (without it, kb cancels: 8*APAD*2 ≡ 0 mod 128).
// Reads apply the same involution on the s-chunk.
#define APAD 72
__global__ __launch_bounds__(256) void attn_mfma(const u16* __restrict__ Qr,
                                                 const u16* __restrict__ Kr,
                                                 const u16* __restrict__ Vr,
                                                 const float* __restrict__ den,
                                                 u16* __restrict__ out, int causal) {
    __shared__ u16 Qs[64 * APAD];
    __shared__ u16 Ks[64 * APAD];
    __shared__ u16 Vs[64 * APAD];   // [d][s'] swizzled
    __shared__ u16 Ps[64 * APAD];
    int lid = blockIdx.x + gridDim.x * blockIdx.y;
    int chunk = (gridDim.x * gridDim.y) >> 3;
    int swz = (lid & 7) * chunk + (lid >> 3);
    int tile = swz % gridDim.x;
    int bh = swz / gridDim.x;
    int b = bh >> 4, h = bh & 15;
    int t0 = tile * 64;
    int tid = threadIdx.x, wave = tid >> 6, lane = tid & 63;
    #pragma unroll
    for (int i = 0; i < 2; ++i) {
        int s = tid + i * 256;
        int r = s >> 3, kb = s & 7;
        *reinterpret_cast<s16x8*>(&Qs[r * APAD + kb * 8]) =
            *reinterpret_cast<const s16x8*>(&Qr[((size_t)bh * TT + t0 + r) * HD + kb * 8]);
    }
    __syncthreads();
    int lr = lane & 15, lk = (lane >> 4) * 8;
    s16x8 qf0 = *reinterpret_cast<const s16x8*>(&Qs[(wave * 16 + lr) * APAD + lk]);
    s16x8 qf1 = *reinterpret_cast<const s16x8*>(&Qs[(wave * 16 + lr) * APAD + 32 + lk]);
    f32x4 accO[4] = {};
    int ntiles = causal ? (tile + 1) : (TT / 64);
    for (int st = 0; st < ntiles; ++st) {
        int s0 = st * 64;
        __syncthreads();
        #pragma unroll
        for (int i = 0; i < 2; ++i) {
            int s = tid + i * 256;
            int r = s >> 3, kb = s & 7;
            *reinterpret_cast<s16x8*>(&Ks[r * APAD + kb * 8]) =
                *reinterpret_cast<const s16x8*>(&Kr[((size_t)bh * TT + s0 + r) * HD + kb * 8]);
            s16x8 vv = *reinterpret_cast<const s16x8*>(&Vr[((size_t)bh * TT + s0 + r) * HD + kb * 8]);
            int sp = (((r >> 3) ^ kb) << 3) + (r & 7);   // swizzled s position
            #pragma unroll
            for (int e = 0; e < 8; ++e)
                Vs[(kb * 8 + e) * APAD + sp] = (u16)vv[e];
        }
        __syncthreads();
        f32x4 accS[4] = {};
        __builtin_amdgcn_s_setprio(1);
        #pragma unroll
        for (int j = 0; j < 4; ++j) {
            s16x8 kb0 = *reinterpret_cast<const s16x8*>(&Ks[(j * 16 + lr) * APAD + lk]);
            s16x8 kb1 = *reinterpret_cast<const s16x8*>(&Ks[(j * 16 + lr) * APAD + 32 + lk]);
            accS[j] = __builtin_amdgcn_mfma_f32_16x16x32_bf16(qf0, kb0, accS[j], 0, 0, 0);
            accS[j] = __builtin_amdgcn_mfma_f32_16x16x32_bf16(qf1, kb1, accS[j], 0, 0, 0);
        }
        __builtin_amdgcn_s_setprio(0);
        int tl = wave * 16 + (lane >> 4) * 4;
        #pragma unroll
        for (int j = 0; j < 4; ++j) {
            #pragma unroll
            for (int r = 0; r < 4; ++r) {
                float v = accS[j][r];
                if (causal && (s0 + j * 16 + lr > t0 + tl + r)) v = 0.f;
                Ps[(tl + r) * APAD + j * 16 + lr] = f2bf(v);
            }
        }
        __syncthreads();
        __builtin_amdgcn_s_setprio(1);
        #pragma unroll
        for (int ks = 0; ks < 2; ++ks) {
            s16x8 pa = *reinterpret_cast<const s16x8*>(&Ps[(wave * 16 + lr) * APAD + ks * 32 + lk]);
            #pragma unroll
            for (int j = 0; j < 4; ++j) {
                int d = j * 16 + lr;
                int c = ks * 4 + (lane >> 4);
                int cp = c ^ ((d >> 3) & 7);
                s16x8 vb = *reinterpret_cast<const s16x8*>(&Vs[d * APAD + cp * 8]);
                accO[j] = __builtin_amdgcn_mfma_f32_16x16x32_bf16(pa, vb, accO[j], 0, 0, 0);
            }
        }
        __builtin_amdgcn_s_setprio(0);
    }
    int tl = wave * 16 + (lane >> 4) * 4;
    float invd[4];
    #pragma unroll
    for (int r = 0; r < 4; ++r) invd[r] = 1.0f / den[bh * TT + t0 + tl + r];
    #pragma unroll
    for (int j = 0; j < 4; ++j)
        #pragma unroll
        for (int r = 0; r < 4; ++r)
            out[(size_t)(b * TT + t0 + tl + r) * CC + h * HD + j * 16 + lr] = f2bf(accO[j][r] * invd[r]);
}

// ---------------------------------------------------------------- launch
extern "C" void kernel_launch(void* const* d_in, const int* in_sizes, int n_in,
                              void* d_out, int out_size, void* d_ws, size_t ws_size,
                              hipStream_t stream) {
    const float* x        = (const float*)d_in[0];
    const float* memory   = (const float*)d_in[1];
    const float* ln1_g    = (const float*)d_in[2];
    const float* ln1_b    = (const float*)d_in[3];
    const float* sa_qkv_w = (const float*)d_in[4];
    const float* sa_qkv_b = (const float*)d_in[5];
    const float* sa_pr_w  = (const float*)d_in[6];
    const float* sa_pr_b  = (const float*)d_in[7];
    const float* ln2_g    = (const float*)d_in[8];
    const float* ln2_b    = (const float*)d_in[9];
    const float* ca_q_w   = (const float*)d_in[10];
    const float* ca_q_b   = (const float*)d_in[11];
    const float* ca_kv_w  = (const float*)d_in[12];
    const float* ca_kv_b  = (const float*)d_in[13];
    const float* ca_pr_w  = (const float*)d_in[14];
    const float* ca_pr_b  = (const float*)d_in[15];
    const float* ln3_g    = (const float*)d_in[16];
    const float* ln3_b    = (const float*)d_in[17];
    const float* fc_w     = (const float*)d_in[18];
    const float* fc_b     = (const float*)d_in[19];
    const float* fcp_w    = (const float*)d_in[20];
    const float* fcp_b    = (const float*)d_in[21];
    float* out = (float*)d_out;
    char* wsb  = (char*)d_ws;

    const size_t MB = 1024 * 1024;
    u16* qkvT  = (u16*)wsb;                  // 6 MB
    u16* prT   = (u16*)(wsb + 6 * MB);       // 2 MB
    u16* caqT  = (u16*)(wsb + 8 * MB);       // 2 MB
    u16* cakvT = (u16*)(wsb + 10 * MB);      // 4 MB
    u16* caprT = (u16*)(wsb + 14 * MB);      // 2 MB
    u16* fcT   = (u16*)(wsb + 16 * MB);      // 8 MB
    u16* fcpT  = (u16*)(wsb + 24 * MB);      // 8 MB
    u16* memB  = (u16*)(wsb + 32 * MB);      // 4 MB
    u16* hB    = (u16*)(wsb + 36 * MB);      // 4 MB
    u16* h2B   = (u16*)(wsb + 40 * MB);      // 4 MB
    u16* Qb    = (u16*)(wsb + 44 * MB);      // 4 MB
    u16* Kb    = (u16*)(wsb + 48 * MB);      // 4 MB
    u16* Vb    = (u16*)(wsb + 52 * MB);      // 4 MB (row-major V)
    float* Pbuf = (float*)(wsb + 44 * MB);   // 16 MB (SPLITK=2 projections), aliases Q/K/V after attn
    u16*   fcB   = (u16*)wsb;                // 16 MB at [0,16) (qkvT..caprT dead by MLP)
    float* Pbuf4 = (float*)(wsb + 40 * MB);  // 32 MB at [40,72) (MLP only)
    float* KsumP = (float*)(wsb + 76 * MB + 65536);    // 64 KB
    float* den   = (float*)(wsb + 76 * MB + 131072);   // 128 KB
    float* cosT  = (float*)(wsb + 76 * MB + 262144);   // 128 KB
    float* sinT  = (float*)(wsb + 76 * MB + 393216);   // 128 KB

    dim3 b256(256), b512(512);
    const int TOT4 = MM * CC / 4;  // 524288

    // fused prep: weight transposes + memory f2b + RoPE tables + LN1
    prep_kernel<<<dim3(8320), b256, 0, stream>>>(
        sa_qkv_w, qkvT, sa_pr_w, prT, ca_q_w, caqT, ca_kv_w, cakvT,
        ca_pr_w, caprT, fc_w, fcT, fcp_w, fcpT, memory, memB, cosT, sinT,
        x, ln1_g, ln1_b, hB);

    // ---- causal self-attention ----
    gemm_bf16<128, 64, M_QKV, 1><<<dim3(48, 16), b512, 0, stream>>>(
        hB, nullptr, qkvT, nullptr, sa_qkv_b, nullptr, nullptr,
        nullptr, Qb, Kb, Vb, KsumP, 3072, 1024);
    denom_rope_kernel<<<dim3(1536), b256, 0, stream>>>(Qb, Kb, KsumP, cosT, sinT, den);
    attn_mfma<<<dim3(16, 32), b256, 0, stream>>>(Qb, Kb, Vb, den, h2B, 1);
    gemm_bf16<64, 64, M_PART, 2><<<dim3(16, 32, 2), b512, 0, stream>>>(
        h2B, nullptr, prT, nullptr, nullptr, nullptr, nullptr,
        Pbuf, nullptr, nullptr, nullptr, nullptr, 1024, 1024);
    reduce_ln_kernel<2><<<dim3(MM), b256, 0, stream>>>(Pbuf, sa_pr_b, x, ln2_g, ln2_b, out, hB);

    // ---- cross-attention ----
    gemm_bf16<128, 64, M_CAQKV, 1><<<dim3(48, 16), b512, 0, stream>>>(
        hB, memB, caqT, cakvT, ca_q_b, ca_kv_b, nullptr,
        nullptr, Qb, Kb, Vb, KsumP, 3072, 1024);
    denom_rope_kernel<<<dim3(1536), b256, 0, stream>>>(Qb, Kb, KsumP, cosT, sinT, den);
    attn_mfma<<<dim3(16, 32), b256, 0, stream>>>(Qb, Kb, Vb, den, h2B, 0);
    gemm_bf16<64, 64, M_PART, 2><<<dim3(16, 32, 2), b512, 0, stream>>>(
        h2B, nullptr, caprT, nullptr, nullptr, nullptr, nullptr,
        Pbuf, nullptr, nullptr, nullptr, nullptr, 1024, 1024);
    reduce_ln_kernel<2><<<dim3(MM), b256, 0, stream>>>(Pbuf, ca_pr_b, out, ln3_g, ln3_b, out, hB);

    // ---- MLP ----
    gemm_bf16<128, 64, M_GELU, 1><<<dim3(64, 16), b512, 0, stream>>>(
        hB, nullptr, fcT, nullptr, fc_b, nullptr, nullptr,
        nullptr, fcB, nullptr, nullptr, nullptr, 4096, 1024);
    gemm_bf16<128, 64, M_PART, 4><<<dim3(16, 16, 4), b512, 0, stream>>>(
        fcB, nullptr, fcpT, nullptr, nullptr, nullptr, nullptr,
        Pbuf4, nullptr, nullptr, nullptr, nullptr, 1024, 4096);
    reduce_res_kernel<4><<<dim3(TOT4 / 256), b256, 0, stream>>>(Pbuf4, fcp_b, out, out, 1024, TOT4);
}

// Round 15
// 223.807 us; speedup vs baseline: 1.0928x; 1.0066x over previous
//
#include <hip/hip_runtime.h>
#include <math.h>

#define BB 2
#define TT 1024
#define CC 1024
#define HH 16
#define HD 64
#define MM (BB*TT)   // 2048 rows

typedef unsigned short u16;
typedef unsigned int u32;
typedef short s16x8 __attribute__((ext_vector_type(8)));
typedef float f32x4 __attribute__((ext_vector_type(4)));

__device__ __forceinline__ u16 f2bf(float f) {
    u32 u = __builtin_bit_cast(u32, f);
    u += 0x7fffu + ((u >> 16) & 1u);
    return (u16)(u >> 16);
}
__device__ __forceinline__ float bf2f(u16 h) {
    return __builtin_bit_cast(float, ((u32)h) << 16);
}
__device__ __forceinline__ void gload16(const void* g, void* l) {
    __builtin_amdgcn_global_load_lds((const __attribute__((address_space(1))) u32*)g,
                                     (__attribute__((address_space(3))) u32*)l, 16, 0, 0);
}
__device__ __forceinline__ float gelu_tanh(float x) {
    float x3 = x * x * x;
    return 0.5f * x * (1.0f + tanhf(0.7978845608028654f * (x + 0.044715f * x3)));
}
__device__ __forceinline__ float elu1(float v) {
    return (v > 0.0f) ? v + 1.0f : expf(v);
}

// ------------------------------------------------- fused prep:
// [0,4096): weight transpose fp32[K][N]->bf16[N][K]; [4096,6144): memory f2b;
// [6144,6272): RoPE tables; [6272,8320): LN1 (x -> hB bf16)
__device__ __forceinline__ void wtile(const float* __restrict__ in, u16* __restrict__ out,
                                      int K, int N, int local, float (*tl)[65]) {
    int tilesX = N >> 6;
    int n0 = (local % tilesX) * 64, k0 = (local / tilesX) * 64;
    int c = threadIdx.x & 63, r4 = threadIdx.x >> 6;
    #pragma unroll
    for (int i = 0; i < 16; ++i) {
        int r = r4 * 16 + i;
        tl[r][c] = in[(size_t)(k0 + r) * N + n0 + c];
    }
    __syncthreads();
    #pragma unroll
    for (int i = 0; i < 16; ++i) {
        int r = r4 * 16 + i;
        out[(size_t)(n0 + r) * K + k0 + c] = f2bf(tl[c][r]);
    }
}

__global__ __launch_bounds__(256) void prep_kernel(
        const float* __restrict__ w_qkv, u16* __restrict__ t_qkv,
        const float* __restrict__ w_pr,  u16* __restrict__ t_pr,
        const float* __restrict__ w_caq, u16* __restrict__ t_caq,
        const float* __restrict__ w_cakv,u16* __restrict__ t_cakv,
        const float* __restrict__ w_capr,u16* __restrict__ t_capr,
        const float* __restrict__ w_fc,  u16* __restrict__ t_fc,
        const float* __restrict__ w_fcp, u16* __restrict__ t_fcp,
        const float* __restrict__ memF,  u16* __restrict__ memB,
        float* __restrict__ cosT, float* __restrict__ sinT,
        const float* __restrict__ x, const float* __restrict__ ln1_g,
        const float* __restrict__ ln1_b, u16* __restrict__ hB) {
    __shared__ float tl[64][65];
    int bid = blockIdx.x;
    if (bid < 768)        wtile(w_qkv,  t_qkv,  1024, 3072, bid, tl);
    else if (bid < 1024)  wtile(w_pr,   t_pr,   1024, 1024, bid - 768, tl);
    else if (bid < 1280)  wtile(w_caq,  t_caq,  1024, 1024, bid - 1024, tl);
    else if (bid < 1792)  wtile(w_cakv, t_cakv, 1024, 2048, bid - 1280, tl);
    else if (bid < 2048)  wtile(w_capr, t_capr, 1024, 1024, bid - 1792, tl);
    else if (bid < 3072)  wtile(w_fc,   t_fc,   1024, 4096, bid - 2048, tl);
    else if (bid < 4096)  wtile(w_fcp,  t_fcp,  4096, 1024, bid - 3072, tl);
    else if (bid < 6144) {
        int i = (bid - 4096) * 256 + threadIdx.x;
        float4 v = reinterpret_cast<const float4*>(memF)[i];
        uint2 p;
        p.x = (u32)f2bf(v.x) | ((u32)f2bf(v.y) << 16);
        p.y = (u32)f2bf(v.z) | ((u32)f2bf(v.w) << 16);
        reinterpret_cast<uint2*>(memB)[i] = p;
    } else if (bid < 6272) {
        int idx = (bid - 6144) * 256 + threadIdx.x;   // 0..32767
        int t = idx >> 5, d = idx & 31;
        double inv = pow(10000.0, -((double)d) / 32.0);
        double ang = (double)t * inv;
        cosT[t * 32 + d] = (float)cos(ang);
        sinT[t * 32 + d] = (float)sin(ang);
    } else {
        // LayerNorm 1: row = bid - 6272
        int row = bid - 6272;
        float4 v = reinterpret_cast<const float4*>(x + (size_t)row * CC)[threadIdx.x];
        float s  = v.x + v.y + v.z + v.w;
        float sq = v.x*v.x + v.y*v.y + v.z*v.z + v.w*v.w;
        #pragma unroll
        for (int off = 32; off >= 1; off >>= 1) {
            s  += __shfl_down(s, off);
            sq += __shfl_down(sq, off);
        }
        __shared__ float ls[4], lsq[4];
        int wave = threadIdx.x >> 6, lane = threadIdx.x & 63;
        if (lane == 0) { ls[wave] = s; lsq[wave] = sq; }
        __syncthreads();
        s  = ls[0] + ls[1] + ls[2] + ls[3];
        sq = lsq[0] + lsq[1] + lsq[2] + lsq[3];
        float mean = s * (1.0f / CC);
        float var  = sq * (1.0f / CC) - mean * mean;
        float rstd = rsqrtf(var + 1e-5f);
        float4 gv = reinterpret_cast<const float4*>(ln1_g)[threadIdx.x];
        float4 bv = reinterpret_cast<const float4*>(ln1_b)[threadIdx.x];
        float o0 = (v.x - mean) * rstd * gv.x + bv.x;
        float o1 = (v.y - mean) * rstd * gv.y + bv.y;
        float o2 = (v.z - mean) * rstd * gv.z + bv.z;
        float o3 = (v.w - mean) * rstd * gv.w + bv.w;
        uint2 p;
        p.x = (u32)f2bf(o0) | ((u32)f2bf(o1) << 16);
        p.y = (u32)f2bf(o2) | ((u32)f2bf(o3) << 16);
        reinterpret_cast<uint2*>(hB + (size_t)row * CC)[threadIdx.x] = p;
    }
}

// ---------------------------------------------------------------- bf16 MFMA GEMM
#define M_F32RES 0
#define M_GELU   1
#define M_QKV    2
#define M_PART   5
#define M_CAQKV  6

template <int MODE>
__device__ __forceinline__ void emit(int row, int col, float v,
                                     const float* __restrict__ res,
                                     float* __restrict__ oF, u16* __restrict__ o1,
                                     u16* __restrict__ o2, u16* __restrict__ o3, int N) {
    if constexpr (MODE == M_F32RES) {
        size_t o = (size_t)row * N + col;
        oF[o] = v + res[o];
    } else if constexpr (MODE == M_GELU) {
        o1[(size_t)row * N + col] = f2bf(gelu_tanh(v));
    } else {  // M_QKV mapping; all packs row-major [bh][t][d] (coalesced)
        int b = row >> 10, t = row & 1023;
        if (col < 1024) {
            int h = col >> 6, d = col & 63;
            o1[(((size_t)(b * HH + h)) * TT + t) * HD + d] = f2bf(elu1(v));
        } else if (col < 2048) {
            int c = col - 1024, h = c >> 6, d = c & 63;
            o2[(((size_t)(b * HH + h)) * TT + t) * HD + d] = f2bf(elu1(v));
        } else {
            int c = col - 2048, h = c >> 6, d = c & 63;
            o3[(((size_t)(b * HH + h)) * TT + t) * HD + d] = f2bf(v);   // V row-major
        }
    }
}

// out = A[M,K] @ BT[N,K]^T (+bias). 512 threads / 8 waves (4x2), templated BK.
// Single-buffer LDS 2-phase; BK=128 where occupancy is grid/wave-limited
// (halves barrier stalls at unchanged blocks/CU). XCD-aware tile swizzle;
// XOR-swizzled LDS via pre-swizzled global source (chunk mask CH-1).
template <int BM, int BN, int BK, int MODE, int SPLITK>
__global__ __launch_bounds__(512, 8) void gemm_bf16(const u16* __restrict__ A,
                                                    const u16* __restrict__ A2,
                                                    const u16* __restrict__ BT,
                                                    const u16* __restrict__ BT2,
                                                    const float* __restrict__ bias,
                                                    const float* __restrict__ bias2,
                                                    const float* __restrict__ res,
                                                    float* __restrict__ oF,
                                                    u16* __restrict__ o1,
                                                    u16* __restrict__ o2,
                                                    u16* __restrict__ o3,
                                                    float* __restrict__ ksumP,
                                                    int N, int K) {
    constexpr int WM = BM / 4, WN = BN / 2;
    constexpr int FI = WM / 16, FJ = WN / 16;
    constexpr int CH = BK / 8;             // 16B chunks per row
    constexpr int IA = BM * CH / 512;
    constexpr int IB = BN * CH / 512;
    __shared__ u16 As[BM * BK];
    __shared__ u16 Bs[BN * BK];
    int tid = threadIdx.x;
    int wave = tid >> 6, lane = tid & 63;
    int wr = wave >> 1, wc = wave & 1;
    int gx = gridDim.x, gy = gridDim.y;
    int lid = blockIdx.x + gx * blockIdx.y;
    int chunk = (gx * gy) >> 3;
    int swz = (lid & 7) * chunk + (lid >> 3);
    int bx = swz % gx, by = swz / gx;
    int row0 = by * BM, col0 = bx * BN;
    const u16* Ause = A;
    const u16* Buse = BT;
    const float* buse = bias;
    if constexpr (MODE == M_CAQKV) {
        if (col0 >= 1024) {
            Ause = A2;
            Buse = BT2 - (size_t)1024 * K;
            buse = bias2 - 1024;
        }
    }
    int kbeg = 0, kcnt = K;
    if constexpr (SPLITK > 1) { kcnt = K / SPLITK; kbeg = blockIdx.z * kcnt; }
    int kend = kbeg + kcnt;

    f32x4 acc[FI][FJ] = {};
    int lr = lane & 15;
    for (int kt = kbeg; kt < kend; kt += BK) {
        __syncthreads();
        #pragma unroll
        for (int i = 0; i < IA; ++i) {
            int s = tid + i * 512;
            int r = s / CH, kb = s % CH;
            int kbs = kb ^ (r & (CH - 1));
            gload16(Ause + (size_t)(row0 + r) * K + kt + kbs * 8, &As[s * 8]);
        }
        #pragma unroll
        for (int i = 0; i < IB; ++i) {
            int s = tid + i * 512;
            int r = s / CH, kb = s % CH;
            int kbs = kb ^ (r & (CH - 1));
            gload16(Buse + (size_t)(col0 + r) * K + kt + kbs * 8, &Bs[s * 8]);
        }
        __syncthreads();
        #pragma unroll
        for (int ks = 0; ks < BK / 32; ++ks) {
            s16x8 a[FI], b[FJ];
            int kc = ks * 4 + (lane >> 4);
            int sw = (kc ^ (lr & (CH - 1))) * 8;
            #pragma unroll
            for (int i = 0; i < FI; ++i)
                a[i] = *reinterpret_cast<const s16x8*>(&As[(wr * WM + i * 16 + lr) * BK + sw]);
            #pragma unroll
            for (int j = 0; j < FJ; ++j)
                b[j] = *reinterpret_cast<const s16x8*>(&Bs[(wc * WN + j * 16 + lr) * BK + sw]);
            __builtin_amdgcn_s_setprio(1);
            #pragma unroll
            for (int i = 0; i < FI; ++i)
                #pragma unroll
                for (int j = 0; j < FJ; ++j)
                    acc[i][j] = __builtin_amdgcn_mfma_f32_16x16x32_bf16(a[i], b[j], acc[i][j], 0, 0, 0);
            __builtin_amdgcn_s_setprio(0);
        }
    }
    int lr4 = (lane >> 4) * 4;
    if constexpr (MODE == M_PART) {
        size_t zoff = (size_t)blockIdx.z * (size_t)(gridDim.y * BM) * N;
        #pragma unroll
        for (int j = 0; j < FJ; ++j) {
            int col = col0 + wc * WN + j * 16 + lr;
            #pragma unroll
            for (int i = 0; i < FI; ++i)
                #pragma unroll
                for (int r = 0; r < 4; ++r) {
                    int row = row0 + wr * WM + i * 16 + lr4 + r;
                    oF[zoff + (size_t)row * N + col] = acc[i][j][r];
                }
        }
    } else {
        constexpr int EM = (MODE == M_CAQKV) ? M_QKV : MODE;
        #pragma unroll
        for (int j = 0; j < FJ; ++j) {
            int col = col0 + wc * WN + j * 16 + lr;
            float bi = buse[col];
            #pragma unroll
            for (int i = 0; i < FI; ++i)
                #pragma unroll
                for (int r = 0; r < 4; ++r) {
                    int row = row0 + wr * WM + i * 16 + lr4 + r;
                    emit<EM>(row, col, acc[i][j][r] + bi, res, oF, o1, o2, o3, N);
                }
        }
        if constexpr (MODE == M_QKV || MODE == M_CAQKV) {
            if (col0 >= 1024 && col0 < 2048) {
                float* scratch = (float*)As;
                float part[FJ];
                #pragma unroll
                for (int j = 0; j < FJ; ++j) {
                    int col = col0 + wc * WN + j * 16 + lr;
                    float bi = buse[col];
                    float p = 0.f;
                    #pragma unroll
                    for (int i = 0; i < FI; ++i)
                        #pragma unroll
                        for (int r = 0; r < 4; ++r)
                            p += elu1(acc[i][j][r] + bi);
                    part[j] = p;
                }
                __syncthreads();
                int contrib = wr * 4 + (lane >> 4);
                #pragma unroll
                for (int j = 0; j < FJ; ++j) {
                    int colLocal = wc * WN + j * 16 + lr;
                    scratch[colLocal * 16 + contrib] = part[j];
                }
                __syncthreads();
                if (tid < BN) {
                    float s = 0.f;
                    #pragma unroll
                    for (int c = 0; c < 16; ++c) s += scratch[tid * 16 + c];
                    ksumP[(size_t)by * 1024 + (col0 - 1024) + tid] = s;
                }
            }
        }
    }
}

// split-K reduce: out = sum_s P[s] + bias + res
template <int S>
__global__ __launch_bounds__(256) void reduce_res_kernel(const float* __restrict__ P,
                                                         const float* __restrict__ bias,
                                                         const float* __restrict__ res,
                                                         float* __restrict__ out,
                                                         int N, int total4) {
    int idx = blockIdx.x * 256 + threadIdx.x;
    if (idx >= total4) return;
    float4 b = reinterpret_cast<const float4*>(bias)[idx & (N / 4 - 1)];
    float4 r = reinterpret_cast<const float4*>(res)[idx];
    float4 a = {b.x + r.x, b.y + r.y, b.z + r.z, b.w + r.w};
    #pragma unroll
    for (int s = 0; s < S; ++s) {
        float4 p = reinterpret_cast<const float4*>(P)[(size_t)s * total4 + idx];
        a.x += p.x; a.y += p.y; a.z += p.z; a.w += p.w;
    }
    reinterpret_cast<float4*>(out)[idx] = a;
}

// fused: out = sum_s P[s] + bias + res ; hout = LN(out)*g + b (bf16)
template <int S>
__global__ __launch_bounds__(256) void reduce_ln_kernel(const float* __restrict__ P,
                                                        const float* __restrict__ bias,
                                                        const float* __restrict__ res,
                                                        const float* __restrict__ g,
                                                        const float* __restrict__ bta,
                                                        float* __restrict__ out,
                                                        u16* __restrict__ hout) {
    int row = blockIdx.x;
    int t = threadIdx.x;
    const int total4 = MM * CC / 4;
    size_t ro4 = (size_t)row * 256 + t;
    float4 b = reinterpret_cast<const float4*>(bias)[t];
    float4 r = reinterpret_cast<const float4*>(res)[ro4];
    float4 a = {b.x + r.x, b.y + r.y, b.z + r.z, b.w + r.w};
    #pragma unroll
    for (int s = 0; s < S; ++s) {
        float4 p = reinterpret_cast<const float4*>(P)[(size_t)s * total4 + ro4];
        a.x += p.x; a.y += p.y; a.z += p.z; a.w += p.w;
    }
    reinterpret_cast<float4*>(out)[ro4] = a;
    float s1 = a.x + a.y + a.z + a.w;
    float sq = a.x*a.x + a.y*a.y + a.z*a.z + a.w*a.w;
    #pragma unroll
    for (int off = 32; off >= 1; off >>= 1) {
        s1 += __shfl_down(s1, off);
        sq += __shfl_down(sq, off);
    }
    __shared__ float ls[4], lsq[4];
    int wave = t >> 6, lane = t & 63;
    if (lane == 0) { ls[wave] = s1; lsq[wave] = sq; }
    __syncthreads();
    s1 = ls[0] + ls[1] + ls[2] + ls[3];
    sq = lsq[0] + lsq[1] + lsq[2] + lsq[3];
    float mean = s1 * (1.0f / CC);
    float var  = sq * (1.0f / CC) - mean * mean;
    float rstd = rsqrtf(var + 1e-5f);
    float4 gv = reinterpret_cast<const float4*>(g)[t];
    float4 bv = reinterpret_cast<const float4*>(bta)[t];
    float o0 = (a.x - mean) * rstd * gv.x + bv.x;
    float o1 = (a.y - mean) * rstd * gv.y + bv.y;
    float o2 = (a.z - mean) * rstd * gv.z + bv.z;
    float o3 = (a.w - mean) * rstd * gv.w + bv.w;
    uint2 pk;
    pk.x = (u32)f2bf(o0) | ((u32)f2bf(o1) << 16);
    pk.y = (u32)f2bf(o2) | ((u32)f2bf(o3) << 16);
    reinterpret_cast<uint2*>(hout + (size_t)row * CC)[t] = pk;
}

// In-place RoPE of one (row, quarter) of a [bh][T][64] bf16 buffer
__device__ __forceinline__ void rope_row(u16* __restrict__ buf, int bh, int t, int q,
                                         const float* __restrict__ cosT,
                                         const float* __restrict__ sinT) {
    int d0 = q * 8;
    size_t base = ((size_t)bh * TT + t) * HD;
    s16x8 lo = *reinterpret_cast<const s16x8*>(&buf[base + d0]);
    s16x8 hi = *reinterpret_cast<const s16x8*>(&buf[base + 32 + d0]);
    const float4* cp = reinterpret_cast<const float4*>(&cosT[t * 32 + d0]);
    const float4* sp = reinterpret_cast<const float4*>(&sinT[t * 32 + d0]);
    float4 c0 = cp[0], c1 = cp[1], s0 = sp[0], s1 = sp[1];
    float cc[8] = {c0.x, c0.y, c0.z, c0.w, c1.x, c1.y, c1.z, c1.w};
    float ss[8] = {s0.x, s0.y, s0.z, s0.w, s1.x, s1.y, s1.z, s1.w};
    s16x8 nlo, nhi;
    #pragma unroll
    for (int e = 0; e < 8; ++e) {
        float l = bf2f((u16)lo[e]), h = bf2f((u16)hi[e]);
        nlo[e] = (short)f2bf(l * cc[e] - h * ss[e]);
        nhi[e] = (short)f2bf(h * cc[e] + l * ss[e]);
    }
    *reinterpret_cast<s16x8*>(&buf[base + d0]) = nlo;
    *reinterpret_cast<s16x8*>(&buf[base + 32 + d0]) = nhi;
}

// fused: blocks [0,1024): den[bh][t] = Q.Ksum (pre-rope), then rope Q rows;
//        blocks [1024,1536): rope K
__global__ __launch_bounds__(256) void denom_rope_kernel(u16* __restrict__ Qb,
                                                         u16* __restrict__ Kb,
                                                         const float* __restrict__ KsumP,
                                                         const float* __restrict__ cosT,
                                                         const float* __restrict__ sinT,
                                                         float* __restrict__ den) {
    int bid = blockIdx.x;
    if (bid < 1024) {
        int bh = bid >> 5;
        int b = bh >> 4, h = bh & 15;
        int t0 = (bid & 31) * 32;
        __shared__ float ks[64];
        if (threadIdx.x < 64) {
            float s = 0.f;
            #pragma unroll
            for (int rb = 0; rb < 8; ++rb)
                s += KsumP[(size_t)(b * 8 + rb) * 1024 + h * 64 + threadIdx.x];
            ks[threadIdx.x] = s;
        }
        __syncthreads();
        int wave = threadIdx.x >> 6, lane = threadIdx.x & 63;
        int rw = lane >> 3, lsub = lane & 7;
        int t = t0 + wave * 8 + rw;
        s16x8 q = *reinterpret_cast<const s16x8*>(&Qb[((size_t)bh * TT + t) * HD + lsub * 8]);
        float p = 0.f;
        #pragma unroll
        for (int e = 0; e < 8; ++e) p += bf2f((u16)q[e]) * ks[lsub * 8 + e];
        p += __shfl_xor(p, 1);
        p += __shfl_xor(p, 2);
        p += __shfl_xor(p, 4);
        if (lsub == 0) den[bh * TT + t] = p;
        __syncthreads();   // all denom reads of this block's Q rows complete
        if (threadIdx.x < 128) {
            int row = threadIdx.x >> 2, qq = threadIdx.x & 3;
            rope_row(Qb, bh, t0 + row, qq, cosT, sinT);
        }
    } else {
        int g = (bid - 1024) * 256 + threadIdx.x;   // 0..131071
        int qq = g & 3;
        int t = (g >> 2) & 1023;
        int bh = g >> 12;
        rope_row(Kb, bh, t, qq, cosT, sinT);
    }
}

// ------------------------------------------------------- MFMA linear attention
// V input row-major [bh][T][64]; transpose into Vs[d][s'] during staging with a
// kb-XOR chunk swizzle (s' = ((s>>3) ^ (d>>3))*8 + (s&7)); reads apply the same
// involution on the s-chunk (verified round 14: conflicts ~0).
#define APAD 72
__global__ __launch_bounds__(256) void attn_mfma(const u16* __restrict__ Qr,
                                                 const u16* __restrict__ Kr,
                                                 const u16* __restrict__ Vr,
                                                 const float* __restrict__ den,
                                                 u16* __restrict__ out, int causal) {
    __shared__ u16 Qs[64 * APAD];
    __shared__ u16 Ks[64 * APAD];
    __shared__ u16 Vs[64 * APAD];   // [d][s'] swizzled
    __shared__ u16 Ps[64 * APAD];
    int lid = blockIdx.x + gridDim.x * blockIdx.y;
    int chunk = (gridDim.x * gridDim.y) >> 3;
    int swz = (lid & 7) * chunk + (lid >> 3);
    int tile = swz % gridDim.x;
    int bh = swz / gridDim.x;
    int b = bh >> 4, h = bh & 15;
    int t0 = tile * 64;
    int tid = threadIdx.x, wave = tid >> 6, lane = tid & 63;
    #pragma unroll
    for (int i = 0; i < 2; ++i) {
        int s = tid + i * 256;
        int r = s >> 3, kb = s & 7;
        *reinterpret_cast<s16x8*>(&Qs[r * APAD + kb * 8]) =
            *reinterpret_cast<const s16x8*>(&Qr[((size_t)bh * TT + t0 + r) * HD + kb * 8]);
    }
    __syncthreads();
    int lr = lane & 15, lk = (lane >> 4) * 8;
    s16x8 qf0 = *reinterpret_cast<const s16x8*>(&Qs[(wave * 16 + lr) * APAD + lk]);
    s16x8 qf1 = *reinterpret_cast<const s16x8*>(&Qs[(wave * 16 + lr) * APAD + 32 + lk]);
    f32x4 accO[4] = {};
    int ntiles = causal ? (tile + 1) : (TT / 64);
    for (int st = 0; st < ntiles; ++st) {
        int s0 = st * 64;
        __syncthreads();
        #pragma unroll
        for (int i = 0; i < 2; ++i) {
            int s = tid + i * 256;
            int r = s >> 3, kb = s & 7;
            *reinterpret_cast<s16x8*>(&Ks[r * APAD + kb * 8]) =
                *reinterpret_cast<const s16x8*>(&Kr[((size_t)bh * TT + s0 + r) * HD + kb * 8]);
            s16x8 vv = *reinterpret_cast<const s16x8*>(&Vr[((size_t)bh * TT + s0 + r) * HD + kb * 8]);
            int sp = (((r >> 3) ^ kb) << 3) + (r & 7);   // swizzled s position
            #pragma unroll
            for (int e = 0; e < 8; ++e)
                Vs[(kb * 8 + e) * APAD + sp] = (u16)vv[e];
        }
        __syncthreads();
        f32x4 accS[4] = {};
        __builtin_amdgcn_s_setprio(1);
        #pragma unroll
        for (int j = 0; j < 4; ++j) {
            s16x8 kb0 = *reinterpret_cast<const s16x8*>(&Ks[(j * 16 + lr) * APAD + lk]);
            s16x8 kb1 = *reinterpret_cast<const s16x8*>(&Ks[(j * 16 + lr) * APAD + 32 + lk]);
            accS[j] = __builtin_amdgcn_mfma_f32_16x16x32_bf16(qf0, kb0, accS[j], 0, 0, 0);
            accS[j] = __builtin_amdgcn_mfma_f32_16x16x32_bf16(qf1, kb1, accS[j], 0, 0, 0);
        }
        __builtin_amdgcn_s_setprio(0);
        int tl = wave * 16 + (lane >> 4) * 4;
        #pragma unroll
        for (int j = 0; j < 4; ++j) {
            #pragma unroll
            for (int r = 0; r < 4; ++r) {
                float v = accS[j][r];
                if (causal && (s0 + j * 16 + lr > t0 + tl + r)) v = 0.f;
                Ps[(tl + r) * APAD + j * 16 + lr] = f2bf(v);
            }
        }
        __syncthreads();
        __builtin_amdgcn_s_setprio(1);
        #pragma unroll
        for (int ks = 0; ks < 2; ++ks) {
            s16x8 pa = *reinterpret_cast<const s16x8*>(&Ps[(wave * 16 + lr) * APAD + ks * 32 + lk]);
            #pragma unroll
            for (int j = 0; j < 4; ++j) {
                int d = j * 16 + lr;
                int c = ks * 4 + (lane >> 4);
                int cp = c ^ ((d >> 3) & 7);
                s16x8 vb = *reinterpret_cast<const s16x8*>(&Vs[d * APAD + cp * 8]);
                accO[j] = __builtin_amdgcn_mfma_f32_16x16x32_bf16(pa, vb, accO[j], 0, 0, 0);
            }
        }
        __builtin_amdgcn_s_setprio(0);
    }
    int tl = wave * 16 + (lane >> 4) * 4;
    float invd[4];
    #pragma unroll
    for (int r = 0; r < 4; ++r) invd[r] = 1.0f / den[bh * TT + t0 + tl + r];
    #pragma unroll
    for (int j = 0; j < 4; ++j)
        #pragma unroll
        for (int r = 0; r < 4; ++r)
            out[(size_t)(b * TT + t0 + tl + r) * CC + h * HD + j * 16 + lr] = f2bf(accO[j][r] * invd[r]);
}

// ---------------------------------------------------------------- launch
extern "C" void kernel_launch(void* const* d_in, const int* in_sizes, int n_in,
                              void* d_out, int out_size, void* d_ws, size_t ws_size,
                              hipStream_t stream) {
    const float* x        = (const float*)d_in[0];
    const float* memory   = (const float*)d_in[1];
    const float* ln1_g    = (const float*)d_in[2];
    const float* ln1_b    = (const float*)d_in[3];
    const float* sa_qkv_w = (const float*)d_in[4];
    const float* sa_qkv_b = (const float*)d_in[5];
    const float* sa_pr_w  = (const float*)d_in[6];
    const float* sa_pr_b  = (const float*)d_in[7];
    const float* ln2_g    = (const float*)d_in[8];
    const float* ln2_b    = (const float*)d_in[9];
    const float* ca_q_w   = (const float*)d_in[10];
    const float* ca_q_b   = (const float*)d_in[11];
    const float* ca_kv_w  = (const float*)d_in[12];
    const float* ca_kv_b  = (const float*)d_in[13];
    const float* ca_pr_w  = (const float*)d_in[14];
    const float* ca_pr_b  = (const float*)d_in[15];
    const float* ln3_g    = (const float*)d_in[16];
    const float* ln3_b    = (const float*)d_in[17];
    const float* fc_w     = (const float*)d_in[18];
    const float* fc_b     = (const float*)d_in[19];
    const float* fcp_w    = (const float*)d_in[20];
    const float* fcp_b    = (const float*)d_in[21];
    float* out = (float*)d_out;
    char* wsb  = (char*)d_ws;

    const size_t MB = 1024 * 1024;
    u16* qkvT  = (u16*)wsb;                  // 6 MB
    u16* prT   = (u16*)(wsb + 6 * MB);       // 2 MB
    u16* caqT  = (u16*)(wsb + 8 * MB);       // 2 MB
    u16* cakvT = (u16*)(wsb + 10 * MB);      // 4 MB
    u16* caprT = (u16*)(wsb + 14 * MB);      // 2 MB
    u16* fcT   = (u16*)(wsb + 16 * MB);      // 8 MB
    u16* fcpT  = (u16*)(wsb + 24 * MB);      // 8 MB
    u16* memB  = (u16*)(wsb + 32 * MB);      // 4 MB
    u16* hB    = (u16*)(wsb + 36 * MB);      // 4 MB
    u16* h2B   = (u16*)(wsb + 40 * MB);      // 4 MB
    u16* Qb    = (u16*)(wsb + 44 * MB);      // 4 MB
    u16* Kb    = (u16*)(wsb + 48 * MB);      // 4 MB
    u16* Vb    = (u16*)(wsb + 52 * MB);      // 4 MB (row-major V)
    float* Pbuf = (float*)(wsb + 44 * MB);   // 16 MB (SPLITK=2 projections), aliases Q/K/V after attn
    u16*   fcB   = (u16*)wsb;                // 16 MB at [0,16) (qkvT..caprT dead by MLP)
    float* Pbuf4 = (float*)(wsb + 40 * MB);  // 32 MB at [40,72) (MLP only)
    float* KsumP = (float*)(wsb + 76 * MB + 65536);    // 64 KB
    float* den   = (float*)(wsb + 76 * MB + 131072);   // 128 KB
    float* cosT  = (float*)(wsb + 76 * MB + 262144);   // 128 KB
    float* sinT  = (float*)(wsb + 76 * MB + 393216);   // 128 KB

    dim3 b256(256), b512(512);
    const int TOT4 = MM * CC / 4;  // 524288

    // fused prep: weight transposes + memory f2b + RoPE tables + LN1
    prep_kernel<<<dim3(8320), b256, 0, stream>>>(
        sa_qkv_w, qkvT, sa_pr_w, prT, ca_q_w, caqT, ca_kv_w, cakvT,
        ca_pr_w, caprT, fc_w, fcT, fcp_w, fcpT, memory, memB, cosT, sinT,
        x, ln1_g, ln1_b, hB);

    // ---- causal self-attention ----
    gemm_bf16<128, 64, 128, M_QKV, 1><<<dim3(48, 16), b512, 0, stream>>>(
        hB, nullptr, qkvT, nullptr, sa_qkv_b, nullptr, nullptr,
        nullptr, Qb, Kb, Vb, KsumP, 3072, 1024);
    denom_rope_kernel<<<dim3(1536), b256, 0, stream>>>(Qb, Kb, KsumP, cosT, sinT, den);
    attn_mfma<<<dim3(16, 32), b256, 0, stream>>>(Qb, Kb, Vb, den, h2B, 1);
    gemm_bf16<64, 64, 128, M_PART, 2><<<dim3(16, 32, 2), b512, 0, stream>>>(
        h2B, nullptr, prT, nullptr, nullptr, nullptr, nullptr,
        Pbuf, nullptr, nullptr, nullptr, nullptr, 1024, 1024);
    reduce_ln_kernel<2><<<dim3(MM), b256, 0, stream>>>(Pbuf, sa_pr_b, x, ln2_g, ln2_b, out, hB);

    // ---- cross-attention ----
    gemm_bf16<128, 64, 128, M_CAQKV, 1><<<dim3(48, 16), b512, 0, stream>>>(
        hB, memB, caqT, cakvT, ca_q_b, ca_kv_b, nullptr,
        nullptr, Qb, Kb, Vb, KsumP, 3072, 1024);
    denom_rope_kernel<<<dim3(1536), b256, 0, stream>>>(Qb, Kb, KsumP, cosT, sinT, den);
    attn_mfma<<<dim3(16, 32), b256, 0, stream>>>(Qb, Kb, Vb, den, h2B, 0);
    gemm_bf16<64, 64, 128, M_PART, 2><<<dim3(16, 32, 2), b512, 0, stream>>>(
        h2B, nullptr, caprT, nullptr, nullptr, nullptr, nullptr,
        Pbuf, nullptr, nullptr, nullptr, nullptr, 1024, 1024);
    reduce_ln_kernel<2><<<dim3(MM), b256, 0, stream>>>(Pbuf, ca_pr_b, out, ln3_g, ln3_b, out, hB);

    // ---- MLP ----
    gemm_bf16<128, 64, 64, M_GELU, 1><<<dim3(64, 16), b512, 0, stream>>>(
        hB, nullptr, fcT, nullptr, fc_b, nullptr, nullptr,
        nullptr, fcB, nullptr, nullptr, nullptr, 4096, 1024);
    gemm_bf16<128, 64, 64, M_PART, 4><<<dim3(16, 16, 4), b512, 0, stream>>>(
        fcB, nullptr, fcpT, nullptr, nullptr, nullptr, nullptr,
        Pbuf4, nullptr, nullptr, nullptr, nullptr, 1024, 4096);
    reduce_res_kernel<4><<<dim3(TOT4 / 256), b256, 0, stream>>>(Pbuf4, fcp_b, out, out, 1024, TOT4);
}